// Round 6
// baseline (10146.912 us; speedup 1.0000x reference)
//
#include <hip/hip_runtime.h>

// ============================================================================
// Conv2Seq round 5: R4 structure + split coherence.
//  - barrier: monotonic counter, RELEASE fence only (writeback, no invalidate)
//  - mutable cross-block data (x-planes, hbuf) read via agent-scope relaxed
//    atomic loads (bypass stale L1/L2); producers use plain stores + release.
//  - immutable weights/enc stay L2-cached across all 60 steps (the R4 killer
//    was acquire-invalidate at every barrier -> 55MB/step refetch).
// Attention trick: keys never materialized; q = W^T h, score = enc . q.
// GEMMs: MFMA 16x16x32 bf16, hi/lo split (x.w ~ xh.wh + xl.wh + xh.wl).
// ============================================================================

#define BB   32
#define TT   2048
#define DIN  64
#define HH   1024
#define DOUT 64
#define NSTEP 60
#define LL1  2045
#define LL2  2038
#define LL3  2023
#define CC1  8
#define CC2  16
#define CC3  32
#define K0   1120     // layer1 K: [ctx32 | prev64 | h1 1024]
#define K12  2080     // layers2/3: [ctx32 | h_prev 1024 | h_own 1024]

typedef unsigned short u16;
typedef unsigned int   u32;
typedef unsigned long long u64;
typedef __attribute__((ext_vector_type(8))) short bf16x8;
typedef __attribute__((ext_vector_type(4))) float f32x4;

union FR { u64 q[2]; bf16x8 v; };

__device__ __forceinline__ float4 ld4(const float* p){ return *(const float4*)p; }
__device__ __forceinline__ u16 f2bf(float x){
  unsigned u = __float_as_uint(x);
  return (u16)((u + 0x7FFFu + ((u>>16)&1u)) >> 16);
}
__device__ __forceinline__ float bf2f(u16 h){ return __uint_as_float(((unsigned)h)<<16); }
__device__ __forceinline__ float bfq(u64 w, int i){
  return __uint_as_float(((u32)((w >> (16*i)) & 0xffffu)) << 16);
}
// coherent-point loads (bypass stale L1/L2) for cross-block mutable data
__device__ __forceinline__ float lda32f(const float* p){
  return __hip_atomic_load(p, __ATOMIC_RELAXED, __HIP_MEMORY_SCOPE_AGENT);
}
__device__ __forceinline__ u64 lda64(const void* p){
  return __hip_atomic_load((const u64*)p, __ATOMIC_RELAXED, __HIP_MEMORY_SCOPE_AGENT);
}

// ---------------------------------------------------------------------------
// conv kernels (one-shot; conv3 emits bf16 enc)
// ---------------------------------------------------------------------------
__global__ __launch_bounds__(256) void conv1_kernel(const float* __restrict__ x,
    const float* __restrict__ w, const float* __restrict__ bias,
    float* __restrict__ out){
  int idx = blockIdx.x*256 + threadIdx.x;
  if (idx >= BB*LL1) return;
  int b = idx / LL1, t = idx % LL1;
  float acc[CC1];
  #pragma unroll
  for (int c=0;c<CC1;++c) acc[c] = bias[c];
  for (int k=0;k<4;++k){
    const float* xr = x + ((size_t)(b*TT + t + k))*DIN;
    for (int d=0; d<DIN; d+=4){
      float4 v = ld4(xr + d);
      #pragma unroll
      for (int c=0;c<CC1;++c){
        acc[c] += v.x * w[((c*DIN+d  )<<2)+k]
                + v.y * w[((c*DIN+d+1)<<2)+k]
                + v.z * w[((c*DIN+d+2)<<2)+k]
                + v.w * w[((c*DIN+d+3)<<2)+k];
      }
    }
  }
  float* o = out + (size_t)idx*CC1;
  #pragma unroll
  for (int c=0;c<CC1;++c) o[c] = fmaxf(acc[c], 0.f);
}

__global__ __launch_bounds__(256) void conv2_kernel(const float* __restrict__ r1,
    const float* __restrict__ w, const float* __restrict__ bias,
    float* __restrict__ out){
  int idx = blockIdx.x*256 + threadIdx.x;
  if (idx >= BB*LL2) return;
  int b = idx / LL2, t = idx % LL2;
  float acc[CC2];
  #pragma unroll
  for (int c=0;c<CC2;++c) acc[c] = bias[c];
  for (int k=0;k<8;++k){
    const float* rr = r1 + ((size_t)(b*LL1 + t + k))*CC1;
    for (int c1=0;c1<CC1;c1+=4){
      float4 v = ld4(rr + c1);
      #pragma unroll
      for (int c=0;c<CC2;++c){
        acc[c] += v.x * w[((c*CC1+c1  )<<3)+k]
                + v.y * w[((c*CC1+c1+1)<<3)+k]
                + v.z * w[((c*CC1+c1+2)<<3)+k]
                + v.w * w[((c*CC1+c1+3)<<3)+k];
      }
    }
  }
  float* o = out + (size_t)idx*CC2;
  #pragma unroll
  for (int c=0;c<CC2;++c) o[c] = fmaxf(acc[c], 0.f);
}

__global__ __launch_bounds__(256) void conv3_kernel(const float* __restrict__ r2,
    const float* __restrict__ w, const float* __restrict__ bias,
    u16* __restrict__ out){
  int idx = blockIdx.x*256 + threadIdx.x;
  if (idx >= BB*LL3) return;
  int b = idx / LL3, t = idx % LL3;
  float acc[CC3];
  #pragma unroll
  for (int c=0;c<CC3;++c) acc[c] = bias[c];
  for (int k=0;k<16;++k){
    const float* rr = r2 + ((size_t)(b*LL2 + t + k))*CC2;
    for (int c2=0;c2<CC2;c2+=4){
      float4 v = ld4(rr + c2);
      #pragma unroll
      for (int c=0;c<CC3;++c){
        acc[c] += v.x * w[((c*CC2+c2  )<<4)+k]
                + v.y * w[((c*CC2+c2+1)<<4)+k]
                + v.z * w[((c*CC2+c2+2)<<4)+k]
                + v.w * w[((c*CC2+c2+3)<<4)+k];
      }
    }
  }
  u16* o = out + (size_t)idx*CC3;
  #pragma unroll
  for (int c=0;c<CC3;++c) o[c] = f2bf(fmaxf(acc[c], 0.f));
}

// ---------------------------------------------------------------------------
// weight prep: row reorder rblk = bid*32 + rl, rl = gate*8+jj,
// grow = gate*1024 + bid*8 + jj. K-order: [wih row (Kih)] ++ [whh row (1024)].
// hi/lo bf16 split.
// ---------------------------------------------------------------------------
__global__ __launch_bounds__(256) void prep_kernel(const float* __restrict__ wih,
    const float* __restrict__ whh, u16* __restrict__ wh, u16* __restrict__ wl,
    int Kih, int Kin){
  const size_t total = (size_t)4096*Kin;
  for (size_t idx = (size_t)blockIdx.x*256 + threadIdx.x; idx < total;
       idx += (size_t)gridDim.x*256){
    int rblk = idx / Kin, k = idx - (size_t)rblk*Kin;
    int bid = rblk>>5, rl = rblk&31, g = rl>>3, jj = rl&7;
    int grow = g*1024 + bid*8 + jj;
    float v = (k < Kih) ? wih[(size_t)grow*Kih + k]
                        : whh[(size_t)grow*HH + (k-Kih)];
    u16 h = f2bf(v);
    wh[idx] = h;
    wl[idx] = f2bf(v - bf2f(h));
  }
}

__global__ __launch_bounds__(256) void bsum_kernel(
    const float* __restrict__ bih1, const float* __restrict__ bhh1,
    const float* __restrict__ bih2, const float* __restrict__ bhh2,
    const float* __restrict__ bih3, const float* __restrict__ bhh3,
    float* __restrict__ bs0, float* __restrict__ bs1, float* __restrict__ bs2){
  int idx = blockIdx.x*256 + threadIdx.x;
  if (idx < 4096)       bs0[idx] = bih1[idx] + bhh1[idx];
  else if (idx < 8192){ int r=idx-4096; bs1[r] = bih2[r] + bhh2[r]; }
  else if (idx < 12288){int r=idx-8192; bs2[r] = bih3[r] + bhh3[r]; }
}

__global__ void barinit_kernel(u32* bar){
  if (threadIdx.x < 128) bar[threadIdx.x] = 0u;
}

// ---------------------------------------------------------------------------
// Persistent sequence kernel
// ---------------------------------------------------------------------------
struct SeqArgs {
  const float *x;
  const float *wa[3];
  const float *wout, *bout;
  const u16 *enc;              // [32][2023][32] bf16 (immutable)
  const u16 *wwh[3], *wwl[3];  // immutable
  const float *bsum[3];        // immutable
  u16 *pl[3][2][2];            // [layer][parity][hi/lo]  (mutable, shared)
  float *hbuf;                 // [3][2][32][1024]        (mutable, shared)
  float *cbuf;                 // [3][32][1024] (block-private)
  float *dout;                 // [32][60][64]
  u32 *cnt;
};

#define SMEM_FLOATS 5376

// monotonic grid barrier: RELEASE fence (writeback) only — no invalidate.
// Consumers of mutable data use bypass atomic loads, so no acquire needed;
// immutable weights/enc stay L2-resident across steps.
__device__ __forceinline__ void gbar(u32* cnt, u32 target){
  __syncthreads();
  if (threadIdx.x == 0){
    __threadfence();   // release: push this block's stores to coherent point
    __hip_atomic_fetch_add(cnt, 1u, __ATOMIC_RELAXED, __HIP_MEMORY_SCOPE_AGENT);
    while (__hip_atomic_load(cnt, __ATOMIC_RELAXED, __HIP_MEMORY_SCOPE_AGENT) < target)
      __builtin_amdgcn_s_sleep(2);
  }
  __syncthreads();
}

// attend for (l,b) parity par: q = wa^T h ; softmax(enc.q) ; ctx -> plane
__device__ void attend_phase(const SeqArgs& A, int l, int par, int b, float* sm){
  const int tid = threadIdx.x;
  const float* wa = A.wa[l];
  const float* h  = A.hbuf + (size_t)((l*2+par)*BB + b)*HH;
  const int Kin = (l==0)? K0 : K12;
  const int str = Kin>>1;          // u32 row stride
  u16* ch = A.pl[l][par][0];
  u16* cl = A.pl[l][par][1];
  float* sh  = sm;          // 1024
  float* sq  = sm + 1024;   // 32
  float* ss  = sm + 1056;   // 2023 (pad 2048)
  float* red = sm + 3104;   // 1024
  float* ctxf= sm + 4128;   // 32

  sh[tid] = lda32f(h + tid);   // h written by gemm blocks elsewhere
  __syncthreads();

  const int cc = tid&31, g = tid>>5;
  float part = 0.f;
  for (int kk=g; kk<HH; kk+=32) part += wa[kk*32+cc]*sh[kk];
  red[tid] = part; __syncthreads();
  if (tid<32){ float s=0.f;
    #pragma unroll
    for (int gg=0; gg<32; ++gg) s += red[gg*32+tid];
    sq[tid]=s; }
  __syncthreads();

  const u16* eb = A.enc + (size_t)b*LL3*CC3;
  float lmax = -1e30f;
  for (int t=tid; t<LL3; t+=1024){
    const u16* er = eb + t*32; float dot=0.f;
    #pragma unroll
    for (int c4=0;c4<8;++c4){
      u64 w = *(const u64*)(er + c4*4);
      dot += bfq(w,0)*sq[c4*4] + bfq(w,1)*sq[c4*4+1]
           + bfq(w,2)*sq[c4*4+2] + bfq(w,3)*sq[c4*4+3];
    }
    ss[t]=dot; lmax=fmaxf(lmax,dot);
  }
  #pragma unroll
  for (int o=32;o>0;o>>=1) lmax = fmaxf(lmax, __shfl_xor(lmax,o));
  if ((tid&63)==0) red[tid>>6] = lmax;
  __syncthreads();
  if (tid==0){ float m=red[0]; for (int w=1;w<16;++w) m=fmaxf(m,red[w]); red[16]=m; }
  __syncthreads();
  const float m = red[16];

  float lsum = 0.f;
  for (int t=tid; t<LL3; t+=1024){ float e=__expf(ss[t]-m); ss[t]=e; lsum+=e; }
  #pragma unroll
  for (int o=32;o>0;o>>=1) lsum += __shfl_xor(lsum,o);
  if ((tid&63)==0) red[32 + (tid>>6)] = lsum;
  __syncthreads();
  if (tid==0){ float z=0.f; for (int w=0;w<16;++w) z+=red[32+w]; red[17]=1.0f/z; }
  __syncthreads();
  const float rZ = red[17];

  float acc = 0.f;
  for (int t=g; t<LL3; t+=32) acc += ss[t]*bf2f(eb[t*32+cc]);
  __syncthreads();
  red[tid] = acc; __syncthreads();
  if (tid<32){ float s=0.f;
    #pragma unroll
    for (int gg=0; gg<32; ++gg) s += red[gg*32+tid];
    ctxf[tid] = s*rZ; }
  __syncthreads();
  if (tid < 16){
    float v0=ctxf[2*tid], v1=ctxf[2*tid+1];
    ((u32*)ch)[(size_t)b*str + tid] = (u32)f2bf(v0) | ((u32)f2bf(v1)<<16);
  } else if (tid < 32){
    int t2 = tid-16;
    float v0=ctxf[2*t2], v1=ctxf[2*t2+1];
    u16 h0=f2bf(v0), h1=f2bf(v1);
    ((u32*)cl)[(size_t)b*str + t2] =
        (u32)f2bf(v0-bf2f(h0)) | ((u32)f2bf(v1-bf2f(h1))<<16);
  }
}

// out phase: y(s) = h3(pn) @ wout^T + bout -> dout[:,s,:] and prev slot of
// layer-1 plane parity pn (consumed by G1(s+1)).
__device__ void out_phase(const SeqArgs& A, int pn, int s, int b, float* sm){
  float* sh = sm; float* red = sm+1024; float* yv = sm+2048;
  const int tid = threadIdx.x;
  sh[tid] = lda32f(A.hbuf + (size_t)((2*2+pn)*BB + b)*HH + tid);
  __syncthreads();
  const int d = tid&63, kg = tid>>6;
  const float* wr = A.wout + (size_t)d*HH + kg*64;
  const float* hh = sh + kg*64;
  float acc = 0.f;
  #pragma unroll
  for (int k=0;k<64;k+=4){ float4 w4=ld4(wr+k); float4 hv=*(const float4*)&hh[k];
    acc += w4.x*hv.x+w4.y*hv.y+w4.z*hv.z+w4.w*hv.w; }
  red[tid]=acc; __syncthreads();
  if (tid<64){
    float y = A.bout[tid];
    #pragma unroll
    for (int kk=0;kk<16;++kk) y += red[kk*64+tid];
    A.dout[((size_t)b*NSTEP+s)*DOUT+tid] = y;
    yv[tid] = y;
  }
  __syncthreads();
  if (tid < 32){
    float v0=yv[2*tid], v1=yv[2*tid+1];
    ((u32*)A.pl[0][pn][0])[(size_t)b*(K0>>1) + 16 + tid] =
        (u32)f2bf(v0) | ((u32)f2bf(v1)<<16);
  } else if (tid < 64){
    int t2 = tid-32;
    float v0=yv[2*t2], v1=yv[2*t2+1];
    u16 h0=f2bf(v0), h1=f2bf(v1);
    ((u32*)A.pl[0][pn][1])[(size_t)b*(K0>>1) + 16 + t2] =
        (u32)f2bf(v0-bf2f(h0)) | ((u32)f2bf(v1-bf2f(h1))<<16);
  }
}

// MFMA GEMM (32 weight rows x 32 batch per block, 128 blocks) + fused cell.
// Weights: plain cached loads (immutable, L2-resident). x planes: bypass
// atomic loads (mutable, written by other blocks last phase).
__device__ void gemm_phase(const SeqArgs& A, int l, int p, int pn, float* sm){
  const int bid = blockIdx.x, tid = threadIdx.x;
  const int Kin = (l==0)? K0 : K12;
  const int nks = Kin >> 5;
  const u16* wh  = A.wwh[l];
  const u16* wlo = A.wwl[l];
  const u16* ih = A.pl[l][p][0];
  const u16* il = A.pl[l][p][1];
  const int wave = tid>>6, lane = tid&63;
  const int wt = wave>>3, xh = (wave>>2)&1, kq = wave&3;
  const int r15 = lane&15, g8 = (lane>>4)<<3;
  const u16* wph = wh  + (size_t)(bid*32 + wt*16 + r15)*Kin + g8;
  const u16* wpl = wlo + (size_t)(bid*32 + wt*16 + r15)*Kin + g8;
  const u16* xph = ih + (size_t)(xh*16 + r15)*Kin + g8;
  const u16* xpl = il + (size_t)(xh*16 + r15)*Kin + g8;

  f32x4 acc = {0.f,0.f,0.f,0.f};
  for (int ks = kq; ks < nks; ks += 4){
    const int o = ks*32;
    bf16x8 bh  = *(const bf16x8*)(wph + o);
    bf16x8 bl  = *(const bf16x8*)(wpl + o);
    FR xh_, xl_;
    xh_.q[0] = lda64(xph+o); xh_.q[1] = lda64(xph+o+4);
    xl_.q[0] = lda64(xpl+o); xl_.q[1] = lda64(xpl+o+4);
    acc = __builtin_amdgcn_mfma_f32_16x16x32_bf16(xh_.v, bh, acc, 0,0,0);
    acc = __builtin_amdgcn_mfma_f32_16x16x32_bf16(xl_.v, bh, acc, 0,0,0);
    acc = __builtin_amdgcn_mfma_f32_16x16x32_bf16(xh_.v, bl, acc, 0,0,0);
  }

  float* red = sm;            // 16*256
  float* sg  = sm + 4096;     // 32*32
  float* hv  = sm + 5120;     // 8*32
  #pragma unroll
  for (int rg=0; rg<4; ++rg) red[wave*256 + lane*4 + rg] = acc[rg];
  __syncthreads();
  {
    const int tile = tid>>8, e = tid&255;
    const int wt2 = tile>>1, xh2 = tile&1;
    const int base = (wt2*8 + xh2*4)*256 + e;
    float v = red[base] + red[base+256] + red[base+512] + red[base+768];
    const int ln = e>>2, rg = e&3;
    // D layout (m89): col=lane&15 -> weight row, row=4*(lane>>4)+reg -> batch
    sg[(wt2*16 + (ln&15))*32 + xh2*16 + ((ln>>4)<<2) + rg] = v;
  }
  __syncthreads();
  if (tid < 256){
    const int b = tid&31, jj = tid>>5;
    const int j = bid*8 + jj;
    const float* bs = A.bsum[l];
    float gi = sg[(0 +jj)*32+b] + bs[j];
    float gf = sg[(8 +jj)*32+b] + bs[1024+j];
    float gg = sg[(16+jj)*32+b] + bs[2048+j];
    float go = sg[(24+jj)*32+b] + bs[3072+j];
    float i_ = 1.f/(1.f+__expf(-gi));
    float f_ = 1.f/(1.f+__expf(-gf));
    float g_ = tanhf(gg);
    float o_ = 1.f/(1.f+__expf(-go));
    float* cb = A.cbuf + ((size_t)l*BB + b)*HH + j;
    float c = f_*cb[0] + i_*g_;
    cb[0] = c;
    float hval = o_*tanhf(c);
    A.hbuf[((size_t)(l*2+pn)*BB + b)*HH + j] = hval;
    hv[jj*32 + b] = hval;
  }
  __syncthreads();
  if (tid < 128){
    const int b = tid&31, pr = tid>>5;
    const int jj0 = pr*2;
    float v0 = hv[jj0*32+b], v1 = hv[(jj0+1)*32+b];
    u16 h0 = f2bf(v0), h1 = f2bf(v1);
    u32 ph  = (u32)h0 | ((u32)h1<<16);
    u32 plq = (u32)f2bf(v0-bf2f(h0)) | ((u32)f2bf(v1-bf2f(h1))<<16);
    const int col = bid*8 + jj0;
    if (l == 0){
      size_t i1 = ((size_t)b*K0  + 96   + col) >> 1;   // own h1, next step
      ((u32*)A.pl[0][pn][0])[i1] = ph;  ((u32*)A.pl[0][pn][1])[i1] = plq;
      size_t i2 = ((size_t)b*K12 + 32   + col) >> 1;   // L2 input, this step
      ((u32*)A.pl[1][p ][0])[i2] = ph;  ((u32*)A.pl[1][p ][1])[i2] = plq;
    } else if (l == 1){
      size_t i1 = ((size_t)b*K12 + 1056 + col) >> 1;   // own h2, next step
      ((u32*)A.pl[1][pn][0])[i1] = ph;  ((u32*)A.pl[1][pn][1])[i1] = plq;
      size_t i2 = ((size_t)b*K12 + 32   + col) >> 1;   // L3 input, this step
      ((u32*)A.pl[2][p ][0])[i2] = ph;  ((u32*)A.pl[2][p ][1])[i2] = plq;
    } else {
      size_t i1 = ((size_t)b*K12 + 1056 + col) >> 1;   // own h3, next step
      ((u32*)A.pl[2][pn][0])[i1] = ph;  ((u32*)A.pl[2][pn][1])[i1] = plq;
    }
  }
}

__global__ __launch_bounds__(1024, 4) void seq_kernel(SeqArgs A){
  __shared__ float sm[SMEM_FLOATS];
  const int bid = blockIdx.x, tid = threadIdx.x;
  const size_t gid = (size_t)bid*1024 + tid;
  const size_t gstr = (size_t)256*1024;
  u32 nb = 0;

  // ---- init ----
  for (size_t i = gid; i < (size_t)3*32*1024; i += gstr){
    size_t l2 = i >> 15, r = i & 32767, b = r >> 10, j = r & 1023;
    A.hbuf[((l2*2+0)*BB + b)*HH + j] = 0.f;
  }
  if (bid < 128){
    for (int t = tid; t < 3*32*8; t += 1024){
      int l2 = t/(32*8), r = t%(32*8), b = r>>3, jj = r&7;
      A.cbuf[((size_t)l2*BB + b)*HH + bid*8 + jj] = 0.f;
    }
  }
  // plane parity0 h-slices = 0: l0 u32 [48,560) ; l1/l2 u32 [528,1040)
  for (size_t i = gid; i < (size_t)32*512; i += gstr){
    size_t b = i >> 9, o = i & 511;
    ((u32*)A.pl[0][0][0])[b*(K0>>1) + 48 + o] = 0u;
    ((u32*)A.pl[0][0][1])[b*(K0>>1) + 48 + o] = 0u;
    ((u32*)A.pl[1][0][0])[b*(K12>>1) + 528 + o] = 0u;
    ((u32*)A.pl[1][0][1])[b*(K12>>1) + 528 + o] = 0u;
    ((u32*)A.pl[2][0][0])[b*(K12>>1) + 528 + o] = 0u;
    ((u32*)A.pl[2][0][1])[b*(K12>>1) + 528 + o] = 0u;
  }
  // prev(0) = x[:, T-1, :] into l0 parity0 u16 [32,96)
  for (size_t i = gid; i < (size_t)BB*DIN; i += gstr){
    size_t b = i >> 6, d = i & 63;
    float v = A.x[(b*TT + (TT-1))*DIN + d];
    u16 h = f2bf(v);
    A.pl[0][0][0][b*K0 + 32 + d] = h;
    A.pl[0][0][1][b*K0 + 32 + d] = f2bf(v - bf2f(h));
  }
  gbar(A.cnt, 256*(++nb));

  // P0: attend layer1 step0 (h=0)
  if (bid >= 128 && bid < 160) attend_phase(A, 0, 0, bid-128, sm);
  gbar(A.cnt, 256*(++nb));

  for (int s = 0; s < NSTEP; ++s){
    const int p = s&1, pn = p^1;
    // P1: G1(s) || att2(s) || att3(s)
    if (bid < 128)        gemm_phase(A, 0, p, pn, sm);
    else if (bid < 160)   attend_phase(A, 1, p, bid-128, sm);
    else if (bid < 192)   attend_phase(A, 2, p, bid-160, sm);
    gbar(A.cnt, 256*(++nb));
    // P2: G2(s) || att1(s+1)
    if (bid < 128)        gemm_phase(A, 1, p, pn, sm);
    else if (bid < 160)   attend_phase(A, 0, pn, bid-128, sm);
    gbar(A.cnt, 256*(++nb));
    // P3: G3(s)
    if (bid < 128)        gemm_phase(A, 2, p, pn, sm);
    gbar(A.cnt, 256*(++nb));
    // P4: y(s) -> dout, prev -> l0 plane parity pn
    if (bid >= 128 && bid < 160) out_phase(A, pn, s, bid-128, sm);
    gbar(A.cnt, 256*(++nb));
  }
}

// ---------------------------------------------------------------------------
extern "C" void kernel_launch(void* const* d_in, const int* in_sizes, int n_in,
                              void* d_out, int out_size, void* d_ws, size_t ws_size,
                              hipStream_t stream) {
  const float* x    = (const float*)d_in[0];
  const float* w_c1 = (const float*)d_in[1];
  const float* b_c1 = (const float*)d_in[2];
  const float* w_c2 = (const float*)d_in[3];
  const float* b_c2 = (const float*)d_in[4];
  const float* w_c3 = (const float*)d_in[5];
  const float* b_c3 = (const float*)d_in[6];

  SeqArgs A;
  A.x     = x;
  A.wa[0] = (const float*)d_in[7];
  A.wa[1] = (const float*)d_in[9];
  A.wa[2] = (const float*)d_in[11];
  const float* wih1 = (const float*)d_in[13];
  const float* whh1 = (const float*)d_in[14];
  const float* bih1 = (const float*)d_in[15];
  const float* bhh1 = (const float*)d_in[16];
  const float* wih2 = (const float*)d_in[17];
  const float* whh2 = (const float*)d_in[18];
  const float* bih2 = (const float*)d_in[19];
  const float* bhh2 = (const float*)d_in[20];
  const float* wih3 = (const float*)d_in[21];
  const float* whh3 = (const float*)d_in[22];
  const float* bih3 = (const float*)d_in[23];
  const float* bhh3 = (const float*)d_in[24];
  A.wout = (const float*)d_in[25];
  A.bout = (const float*)d_in[26];
  A.dout = (float*)d_out;

  char* base = (char*)d_ws;
  size_t off = 0;
  auto alloc = [&](size_t bytes)->char*{
    char* pp = base + off; off = (off + bytes + 255) & ~(size_t)255; return pp;
  };

  u16* enc = (u16*)alloc((size_t)BB*LL3*CC3*2);            // 4.14 MB
  A.enc  = enc;
  A.hbuf = (float*)alloc((size_t)3*2*BB*HH*4);             // 0.79 MB
  A.cbuf = (float*)alloc((size_t)3*BB*HH*4);               // 0.39 MB
  for (int l=0;l<3;++l){
    size_t kin = (l==0)? K0 : K12;
    for (int par=0; par<2; ++par)
      for (int hl=0; hl<2; ++hl)
        A.pl[l][par][hl] = (u16*)alloc((size_t)BB*kin*2);
  }
  float* bs0 = (float*)alloc(4096*4);
  float* bs1 = (float*)alloc(4096*4);
  float* bs2 = (float*)alloc(4096*4);
  A.bsum[0]=bs0; A.bsum[1]=bs1; A.bsum[2]=bs2;
  A.cnt  = (u32*)alloc(512);
  u16 *wp[6];
  wp[0] = (u16*)alloc((size_t)4096*K0*2);                  // 9.18 MB
  wp[1] = (u16*)alloc((size_t)4096*K0*2);
  wp[2] = (u16*)alloc((size_t)4096*K12*2);                 // 17.04 MB
  wp[3] = (u16*)alloc((size_t)4096*K12*2);
  wp[4] = (u16*)alloc((size_t)4096*K12*2);
  wp[5] = (u16*)alloc((size_t)4096*K12*2);
  A.wwh[0]=wp[0]; A.wwl[0]=wp[1];
  A.wwh[1]=wp[2]; A.wwl[1]=wp[3];
  A.wwh[2]=wp[4]; A.wwl[2]=wp[5];
  // total ~93.2 MB

  // conv temps alias the layer-1 weight buffers (preps run after convs)
  float* r1 = (float*)wp[0];                         // 2.09 MB < 9.18 MB
  float* r2 = (float*)(((char*)wp[0]) + 2095104);    // 4.17 MB, still in wp[0]

  conv1_kernel<<<(BB*LL1+255)/256, 256, 0, stream>>>(x, w_c1, b_c1, r1);
  conv2_kernel<<<(BB*LL2+255)/256, 256, 0, stream>>>(r1, w_c2, b_c2, r2);
  conv3_kernel<<<(BB*LL3+255)/256, 256, 0, stream>>>(r2, w_c3, b_c3, enc);
  prep_kernel<<<2048, 256, 0, stream>>>(wih1, whh1, wp[0], wp[1],   96, K0);
  prep_kernel<<<2048, 256, 0, stream>>>(wih2, whh2, wp[2], wp[3], 1056, K12);
  prep_kernel<<<2048, 256, 0, stream>>>(wih3, whh3, wp[4], wp[5], 1056, K12);
  bsum_kernel<<<48, 256, 0, stream>>>(bih1,bhh1,bih2,bhh2,bih3,bhh3, bs0,bs1,bs2);
  barinit_kernel<<<1, 256, 0, stream>>>(A.cnt);

  void* params[] = { (void*)&A };
  hipLaunchCooperativeKernel((const void*)seq_kernel, dim3(256), dim3(1024),
                             params, 0, stream);
}

// Round 7
// 9988.684 us; speedup vs baseline: 1.0158x; 1.0158x over previous
//
#include <hip/hip_runtime.h>

// ============================================================================
// Conv2Seq round 6: persistent kernel; distributed-slot grid barrier (no RMW
// contention, no threadfence): arrivals = per-block slot stores (RELEASE),
// block0 wave0 sweeps slots and posts `go`; spinners poll `go` RELAXED (no L2
// invalidate -> weights/enc stay L2-resident). All mutable cross-block data
// via agent-scope relaxed atomic load/store (coherent point). 4 barriers/step.
// GEMM K padded to 128-multiple, fully unrolled MFMA loop (deep prefetch).
// Attention trick: keys never materialized; q = W^T h, score = enc . q.
// ============================================================================

#define BB   32
#define TT   2048
#define DIN  64
#define HH   1024
#define DOUT 64
#define NSTEP 60
#define LL1  2045
#define LL2  2038
#define LL3  2023
#define CC1  8
#define CC2  16
#define CC3  32
#define K0   1120     // layer1 real K: [ctx32 | prev64 | h1 1024]
#define K12  2080     // layers2/3 real K: [ctx32 | h_prev 1024 | h_own 1024]
#define KP0  1152     // padded (36 chunks of 32)
#define KP12 2176     // padded (68 chunks of 32)

typedef unsigned short u16;
typedef unsigned int   u32;
typedef unsigned long long u64;
typedef __attribute__((ext_vector_type(8))) short bf16x8;
typedef __attribute__((ext_vector_type(4))) float f32x4;

union FR { u64 q[2]; bf16x8 v; };

__device__ __forceinline__ float4 ld4(const float* p){ return *(const float4*)p; }
__device__ __forceinline__ u16 f2bf(float x){
  unsigned u = __float_as_uint(x);
  return (u16)((u + 0x7FFFu + ((u>>16)&1u)) >> 16);
}
__device__ __forceinline__ float bf2f(u16 h){ return __uint_as_float(((unsigned)h)<<16); }
__device__ __forceinline__ float bfq(u64 w, int i){
  return __uint_as_float(((u32)((w >> (16*i)) & 0xffffu)) << 16);
}
// coherent-point accessors (bypass stale L1/L2) for cross-block mutable data
__device__ __forceinline__ float lda32f(const float* p){
  return __hip_atomic_load(p, __ATOMIC_RELAXED, __HIP_MEMORY_SCOPE_AGENT);
}
__device__ __forceinline__ u32 lda32u(const u32* p){
  return __hip_atomic_load(p, __ATOMIC_RELAXED, __HIP_MEMORY_SCOPE_AGENT);
}
__device__ __forceinline__ u64 lda64(const void* p){
  return __hip_atomic_load((const u64*)p, __ATOMIC_RELAXED, __HIP_MEMORY_SCOPE_AGENT);
}
__device__ __forceinline__ void sta32(u32* p, u32 v){
  __hip_atomic_store(p, v, __ATOMIC_RELAXED, __HIP_MEMORY_SCOPE_AGENT);
}
__device__ __forceinline__ void sta32f(float* p, float v){
  __hip_atomic_store(p, v, __ATOMIC_RELAXED, __HIP_MEMORY_SCOPE_AGENT);
}

// ---------------------------------------------------------------------------
// conv kernels (one-shot; conv3 emits bf16 enc)
// ---------------------------------------------------------------------------
__global__ __launch_bounds__(256) void conv1_kernel(const float* __restrict__ x,
    const float* __restrict__ w, const float* __restrict__ bias,
    float* __restrict__ out){
  int idx = blockIdx.x*256 + threadIdx.x;
  if (idx >= BB*LL1) return;
  int b = idx / LL1, t = idx % LL1;
  float acc[CC1];
  #pragma unroll
  for (int c=0;c<CC1;++c) acc[c] = bias[c];
  for (int k=0;k<4;++k){
    const float* xr = x + ((size_t)(b*TT + t + k))*DIN;
    for (int d=0; d<DIN; d+=4){
      float4 v = ld4(xr + d);
      #pragma unroll
      for (int c=0;c<CC1;++c){
        acc[c] += v.x * w[((c*DIN+d  )<<2)+k]
                + v.y * w[((c*DIN+d+1)<<2)+k]
                + v.z * w[((c*DIN+d+2)<<2)+k]
                + v.w * w[((c*DIN+d+3)<<2)+k];
      }
    }
  }
  float* o = out + (size_t)idx*CC1;
  #pragma unroll
  for (int c=0;c<CC1;++c) o[c] = fmaxf(acc[c], 0.f);
}

__global__ __launch_bounds__(256) void conv2_kernel(const float* __restrict__ r1,
    const float* __restrict__ w, const float* __restrict__ bias,
    float* __restrict__ out){
  int idx = blockIdx.x*256 + threadIdx.x;
  if (idx >= BB*LL2) return;
  int b = idx / LL2, t = idx % LL2;
  float acc[CC2];
  #pragma unroll
  for (int c=0;c<CC2;++c) acc[c] = bias[c];
  for (int k=0;k<8;++k){
    const float* rr = r1 + ((size_t)(b*LL1 + t + k))*CC1;
    for (int c1=0;c1<CC1;c1+=4){
      float4 v = ld4(rr + c1);
      #pragma unroll
      for (int c=0;c<CC2;++c){
        acc[c] += v.x * w[((c*CC1+c1  )<<3)+k]
                + v.y * w[((c*CC1+c1+1)<<3)+k]
                + v.z * w[((c*CC1+c1+2)<<3)+k]
                + v.w * w[((c*CC1+c1+3)<<3)+k];
      }
    }
  }
  float* o = out + (size_t)idx*CC2;
  #pragma unroll
  for (int c=0;c<CC2;++c) o[c] = fmaxf(acc[c], 0.f);
}

__global__ __launch_bounds__(256) void conv3_kernel(const float* __restrict__ r2,
    const float* __restrict__ w, const float* __restrict__ bias,
    u16* __restrict__ out){
  int idx = blockIdx.x*256 + threadIdx.x;
  if (idx >= BB*LL3) return;
  int b = idx / LL3, t = idx % LL3;
  float acc[CC3];
  #pragma unroll
  for (int c=0;c<CC3;++c) acc[c] = bias[c];
  for (int k=0;k<16;++k){
    const float* rr = r2 + ((size_t)(b*LL2 + t + k))*CC2;
    for (int c2=0;c2<CC2;c2+=4){
      float4 v = ld4(rr + c2);
      #pragma unroll
      for (int c=0;c<CC3;++c){
        acc[c] += v.x * w[((c*CC2+c2  )<<4)+k]
                + v.y * w[((c*CC2+c2+1)<<4)+k]
                + v.z * w[((c*CC2+c2+2)<<4)+k]
                + v.w * w[((c*CC2+c2+3)<<4)+k];
      }
    }
  }
  u16* o = out + (size_t)idx*CC3;
  #pragma unroll
  for (int c=0;c<CC3;++c) o[c] = f2bf(fmaxf(acc[c], 0.f));
}

// ---------------------------------------------------------------------------
// weight prep: row reorder rblk = bid*32 + rl, rl = gate*8+jj,
// grow = gate*1024 + bid*8 + jj. K-order: [wih (Kih)] ++ [whh (1024)] ++ pad0.
// hi/lo bf16 split. Row stride = padded KP.
// ---------------------------------------------------------------------------
__global__ __launch_bounds__(256) void prep_kernel(const float* __restrict__ wih,
    const float* __restrict__ whh, u16* __restrict__ wh, u16* __restrict__ wl,
    int Kih, int Kin, int KPp){
  const size_t total = (size_t)4096*KPp;
  for (size_t idx = (size_t)blockIdx.x*256 + threadIdx.x; idx < total;
       idx += (size_t)gridDim.x*256){
    int rblk = idx / KPp, k = idx - (size_t)rblk*KPp;
    int bid = rblk>>5, rl = rblk&31, g = rl>>3, jj = rl&7;
    int grow = g*1024 + bid*8 + jj;
    float v = 0.f;
    if (k < Kih)      v = wih[(size_t)grow*Kih + k];
    else if (k < Kin) v = whh[(size_t)grow*HH + (k-Kih)];
    u16 h = f2bf(v);
    wh[idx] = h;
    wl[idx] = f2bf(v - bf2f(h));
  }
}

__global__ __launch_bounds__(256) void bsum_kernel(
    const float* __restrict__ bih1, const float* __restrict__ bhh1,
    const float* __restrict__ bih2, const float* __restrict__ bhh2,
    const float* __restrict__ bih3, const float* __restrict__ bhh3,
    float* __restrict__ bs0, float* __restrict__ bs1, float* __restrict__ bs2){
  int idx = blockIdx.x*256 + threadIdx.x;
  if (idx < 4096)       bs0[idx] = bih1[idx] + bhh1[idx];
  else if (idx < 8192){ int r=idx-4096; bs1[r] = bih2[r] + bhh2[r]; }
  else if (idx < 12288){int r=idx-8192; bs2[r] = bih3[r] + bhh3[r]; }
}

__global__ void barinit_kernel(u32* bar){
  for (int i = threadIdx.x; i < 512; i += 256) bar[i] = 0u;
}

// ---------------------------------------------------------------------------
// Persistent sequence kernel
// ---------------------------------------------------------------------------
struct SeqArgs {
  const float *x;
  const float *wa[3];
  const float *wout, *bout;
  const u16 *enc;              // [32][2023][32] bf16 (immutable)
  const u16 *wwh[3], *wwl[3];  // immutable, padded rows
  const float *bsum[3];        // immutable
  u16 *pl[3][2][2];            // [layer][parity][hi/lo], row stride KP
  float *hbuf;                 // [3][2][32][1024]  (mutable, shared)
  float *cbuf;                 // [3][32][1024] (block-private)
  float *dout;                 // [32][60][64]
  u32 *slots;                  // [256] arrival epochs
  u32 *go;                     // release word
};

#define SMEM_FLOATS 5376

// distributed-slot grid barrier; no fences except RELEASE on the slot store.
__device__ __forceinline__ void gbar(const SeqArgs& A, u32 nb){
  asm volatile("s_waitcnt vmcnt(0)" ::: "memory");
  __syncthreads();
  const int bid = blockIdx.x, tid = threadIdx.x;
  if (tid == 0)
    __hip_atomic_store(A.slots + bid, nb, __ATOMIC_RELEASE,
                       __HIP_MEMORY_SCOPE_AGENT);
  if (bid == 0){
    if (tid < 64){
      for (;;){
        u32 v0 = lda32u(A.slots + tid);
        u32 v1 = lda32u(A.slots + 64 + tid);
        u32 v2 = lda32u(A.slots + 128 + tid);
        u32 v3 = lda32u(A.slots + 192 + tid);
        u32 mn = min(min(v0,v1), min(v2,v3));
        if (__all(mn >= nb)) break;
        __builtin_amdgcn_s_sleep(4);
      }
      if (tid == 0) sta32(A.go, nb);
    }
  } else if (tid == 0){
    while (lda32u(A.go) < nb) __builtin_amdgcn_s_sleep(4);
  }
  __syncthreads();
}

// attend for (l,b) parity par: q = wa^T h ; softmax(enc.q) ; ctx -> plane
__device__ void attend_phase(const SeqArgs& A, int l, int par, int b, float* sm){
  const int tid = threadIdx.x;
  const float* wa = A.wa[l];
  const float* h  = A.hbuf + (size_t)((l*2+par)*BB + b)*HH;
  const int strU = ((l==0)? KP0 : KP12) >> 1;   // u32 row stride
  u16* ch = A.pl[l][par][0];
  u16* cl = A.pl[l][par][1];
  float* sh  = sm;          // 1024
  float* sq  = sm + 1024;   // 32
  float* ss  = sm + 1056;   // 2023 (pad 2048)
  float* red = sm + 3104;   // 1024
  float* ctxf= sm + 4128;   // 32

  sh[tid] = lda32f(h + tid);
  __syncthreads();

  const int cc = tid&31, g = tid>>5;
  float part = 0.f;
  for (int kk=g; kk<HH; kk+=32) part += wa[kk*32+cc]*sh[kk];
  red[tid] = part; __syncthreads();
  if (tid<32){ float s=0.f;
    #pragma unroll
    for (int gg=0; gg<32; ++gg) s += red[gg*32+tid];
    sq[tid]=s; }
  __syncthreads();

  const u16* eb = A.enc + (size_t)b*LL3*CC3;
  float lmax = -1e30f;
  for (int t=tid; t<LL3; t+=1024){
    const u16* er = eb + t*32; float dot=0.f;
    #pragma unroll
    for (int c4=0;c4<8;++c4){
      u64 w = *(const u64*)(er + c4*4);
      dot += bfq(w,0)*sq[c4*4] + bfq(w,1)*sq[c4*4+1]
           + bfq(w,2)*sq[c4*4+2] + bfq(w,3)*sq[c4*4+3];
    }
    ss[t]=dot; lmax=fmaxf(lmax,dot);
  }
  #pragma unroll
  for (int o=32;o>0;o>>=1) lmax = fmaxf(lmax, __shfl_xor(lmax,o));
  if ((tid&63)==0) red[tid>>6] = lmax;
  __syncthreads();
  if (tid==0){ float m=red[0]; for (int w=1;w<16;++w) m=fmaxf(m,red[w]); red[16]=m; }
  __syncthreads();
  const float m = red[16];

  float lsum = 0.f;
  for (int t=tid; t<LL3; t+=1024){ float e=__expf(ss[t]-m); ss[t]=e; lsum+=e; }
  #pragma unroll
  for (int o=32;o>0;o>>=1) lsum += __shfl_xor(lsum,o);
  if ((tid&63)==0) red[32 + (tid>>6)] = lsum;
  __syncthreads();
  if (tid==0){ float z=0.f; for (int w=0;w<16;++w) z+=red[32+w]; red[17]=1.0f/z; }
  __syncthreads();
  const float rZ = red[17];

  float acc = 0.f;
  for (int t=g; t<LL3; t+=32) acc += ss[t]*bf2f(eb[t*32+cc]);
  __syncthreads();
  red[tid] = acc; __syncthreads();
  if (tid<32){ float s=0.f;
    #pragma unroll
    for (int gg=0; gg<32; ++gg) s += red[gg*32+tid];
    ctxf[tid] = s*rZ; }
  __syncthreads();
  if (tid < 16){
    float v0=ctxf[2*tid], v1=ctxf[2*tid+1];
    sta32((u32*)ch + (size_t)b*strU + tid, (u32)f2bf(v0) | ((u32)f2bf(v1)<<16));
  } else if (tid < 32){
    int t2 = tid-16;
    float v0=ctxf[2*t2], v1=ctxf[2*t2+1];
    u16 h0=f2bf(v0), h1=f2bf(v1);
    sta32((u32*)cl + (size_t)b*strU + t2,
          (u32)f2bf(v0-bf2f(h0)) | ((u32)f2bf(v1-bf2f(h1))<<16));
  }
}

// out phase: y(s) = h3(pn) @ wout^T + bout -> dout[:,s,:] and prev slot of
// layer-1 plane parity pn (consumed by G1(s+1)).
__device__ void out_phase(const SeqArgs& A, int pn, int s, int b, float* sm){
  float* sh = sm; float* red = sm+1024; float* yv = sm+2048;
  const int tid = threadIdx.x;
  sh[tid] = lda32f(A.hbuf + (size_t)((2*2+pn)*BB + b)*HH + tid);
  __syncthreads();
  const int d = tid&63, kg = tid>>6;
  const float* wr = A.wout + (size_t)d*HH + kg*64;
  const float* hh = sh + kg*64;
  float acc = 0.f;
  #pragma unroll
  for (int k=0;k<64;k+=4){ float4 w4=ld4(wr+k); float4 hv=*(const float4*)&hh[k];
    acc += w4.x*hv.x+w4.y*hv.y+w4.z*hv.z+w4.w*hv.w; }
  red[tid]=acc; __syncthreads();
  if (tid<64){
    float y = A.bout[tid];
    #pragma unroll
    for (int kk=0;kk<16;++kk) y += red[kk*64+tid];
    A.dout[((size_t)b*NSTEP+s)*DOUT+tid] = y;
    yv[tid] = y;
  }
  __syncthreads();
  if (tid < 32){
    float v0=yv[2*tid], v1=yv[2*tid+1];
    sta32((u32*)A.pl[0][pn][0] + (size_t)b*(KP0>>1) + 16 + tid,
          (u32)f2bf(v0) | ((u32)f2bf(v1)<<16));
  } else if (tid < 64){
    int t2 = tid-32;
    float v0=yv[2*t2], v1=yv[2*t2+1];
    u16 h0=f2bf(v0), h1=f2bf(v1);
    sta32((u32*)A.pl[0][pn][1] + (size_t)b*(KP0>>1) + 16 + t2,
          (u32)f2bf(v0-bf2f(h0)) | ((u32)f2bf(v1-bf2f(h1))<<16));
  }
}

// MFMA GEMM (32 weight rows x 32 batch per block, 128 blocks) + fused cell.
// Weights: plain cached loads. x planes: bypass atomic loads. K fully
// unrolled (padded) -> compiler prefetches deep.
template<int L, int KPL, int NIT>
__device__ void gemm_phase(const SeqArgs& A, int p, int pn, float* sm){
  const int bid = blockIdx.x, tid = threadIdx.x;
  const u16* wh  = A.wwh[L];
  const u16* wlo = A.wwl[L];
  const u16* ih = A.pl[L][p][0];
  const u16* il = A.pl[L][p][1];
  const int wave = tid>>6, lane = tid&63;
  const int wt = wave>>3, xh = (wave>>2)&1, kq = wave&3;
  const int r15 = lane&15, g8 = (lane>>4)<<3;
  const u16* wph = wh  + (size_t)(bid*32 + wt*16 + r15)*KPL + g8 + kq*32;
  const u16* wpl = wlo + (size_t)(bid*32 + wt*16 + r15)*KPL + g8 + kq*32;
  const u16* xb  = ih + (size_t)(xh*16 + r15)*KPL + g8 + kq*32;
  const u16* xlb = il + (size_t)(xh*16 + r15)*KPL + g8 + kq*32;

  f32x4 acc0 = {0.f,0.f,0.f,0.f}, acc1 = {0.f,0.f,0.f,0.f};
  #pragma unroll
  for (int it = 0; it < NIT; ++it){
    const int o = it*128;
    bf16x8 bh  = *(const bf16x8*)(wph + o);
    bf16x8 bl  = *(const bf16x8*)(wpl + o);
    FR xh_, xl_;
    xh_.q[0] = lda64(xb+o);  xh_.q[1] = lda64(xb+o+4);
    xl_.q[0] = lda64(xlb+o); xl_.q[1] = lda64(xlb+o+4);
    acc0 = __builtin_amdgcn_mfma_f32_16x16x32_bf16(xh_.v, bh, acc0, 0,0,0);
    acc1 = __builtin_amdgcn_mfma_f32_16x16x32_bf16(xl_.v, bh, acc1, 0,0,0);
    acc0 = __builtin_amdgcn_mfma_f32_16x16x32_bf16(xh_.v, bl, acc0, 0,0,0);
  }
  f32x4 acc = acc0 + acc1;

  float* red = sm;            // 16*256
  float* sg  = sm + 4096;     // 32*32
  float* hv  = sm + 5120;     // 8*32
  #pragma unroll
  for (int rg=0; rg<4; ++rg) red[wave*256 + lane*4 + rg] = acc[rg];
  __syncthreads();
  {
    const int tile = tid>>8, e = tid&255;
    const int wt2 = tile>>1, xh2 = tile&1;
    const int base = (wt2*8 + xh2*4)*256 + e;
    float v = red[base] + red[base+256] + red[base+512] + red[base+768];
    const int ln = e>>2, rg = e&3;
    // D layout (m89): col=lane&15 -> weight row, row=4*(lane>>4)+reg -> batch
    sg[(wt2*16 + (ln&15))*32 + xh2*16 + ((ln>>4)<<2) + rg] = v;
  }
  __syncthreads();
  if (tid < 256){
    const int b = tid&31, jj = tid>>5;
    const int j = bid*8 + jj;
    const float* bs = A.bsum[L];
    float gi = sg[(0 +jj)*32+b] + bs[j];
    float gf = sg[(8 +jj)*32+b] + bs[1024+j];
    float gg = sg[(16+jj)*32+b] + bs[2048+j];
    float go = sg[(24+jj)*32+b] + bs[3072+j];
    float i_ = 1.f/(1.f+__expf(-gi));
    float f_ = 1.f/(1.f+__expf(-gf));
    float g_ = tanhf(gg);
    float o_ = 1.f/(1.f+__expf(-go));
    float* cb = A.cbuf + ((size_t)L*BB + b)*HH + j;
    float c = f_*cb[0] + i_*g_;
    cb[0] = c;
    float hval = o_*tanhf(c);
    sta32f(A.hbuf + ((size_t)(L*2+pn)*BB + b)*HH + j, hval);
    hv[jj*32 + b] = hval;
  }
  __syncthreads();
  if (tid < 128){
    const int b = tid&31, pr = tid>>5;
    const int jj0 = pr*2;
    float v0 = hv[jj0*32+b], v1 = hv[(jj0+1)*32+b];
    u16 h0 = f2bf(v0), h1 = f2bf(v1);
    u32 ph  = (u32)h0 | ((u32)h1<<16);
    u32 plq = (u32)f2bf(v0-bf2f(h0)) | ((u32)f2bf(v1-bf2f(h1))<<16);
    const int col = bid*8 + jj0;
    if (L == 0){
      size_t i1 = ((size_t)b*KP0  + 96   + col) >> 1;   // own h1, next step
      sta32((u32*)A.pl[0][pn][0] + i1, ph);  sta32((u32*)A.pl[0][pn][1] + i1, plq);
      size_t i2 = ((size_t)b*KP12 + 32   + col) >> 1;   // L2 input, this step
      sta32((u32*)A.pl[1][p ][0] + i2, ph);  sta32((u32*)A.pl[1][p ][1] + i2, plq);
    } else if (L == 1){
      size_t i1 = ((size_t)b*KP12 + 1056 + col) >> 1;   // own h2, next step
      sta32((u32*)A.pl[1][pn][0] + i1, ph);  sta32((u32*)A.pl[1][pn][1] + i1, plq);
      size_t i2 = ((size_t)b*KP12 + 32   + col) >> 1;   // L3 input, this step
      sta32((u32*)A.pl[2][p ][0] + i2, ph);  sta32((u32*)A.pl[2][p ][1] + i2, plq);
    } else {
      size_t i1 = ((size_t)b*KP12 + 1056 + col) >> 1;   // own h3, next step
      sta32((u32*)A.pl[2][pn][0] + i1, ph);  sta32((u32*)A.pl[2][pn][1] + i1, plq);
    }
  }
}

__global__ __launch_bounds__(1024, 4) void seq_kernel(SeqArgs A){
  __shared__ float sm[SMEM_FLOATS];
  const int bid = blockIdx.x, tid = threadIdx.x;
  const size_t gid = (size_t)bid*1024 + tid;
  const size_t gstr = (size_t)256*1024;
  u32 nb = 0;

  // ---- init: zero ALL planes (both parities, hi/lo, incl pads), hbuf par0,
  //      cbuf (block-private). prev/ctx filled in P0 after the barrier. ----
  {
    const size_t n0 = (size_t)32*(KP0>>1);      // u32 per l0 buffer
    const size_t n1 = (size_t)32*(KP12>>1);     // u32 per l1/l2 buffer
    for (size_t i = gid; i < n0; i += gstr){
      #pragma unroll
      for (int q=0;q<2;++q)
        #pragma unroll
        for (int hl=0;hl<2;++hl)
          sta32((u32*)A.pl[0][q][hl] + i, 0u);
    }
    for (size_t i = gid; i < n1; i += gstr){
      #pragma unroll
      for (int q=0;q<2;++q)
        #pragma unroll
        for (int hl=0;hl<2;++hl){
          sta32((u32*)A.pl[1][q][hl] + i, 0u);
          sta32((u32*)A.pl[2][q][hl] + i, 0u);
        }
    }
  }
  for (size_t i = gid; i < (size_t)3*32*1024; i += gstr){
    size_t l2 = i >> 15, r = i & 32767, b = r >> 10, j = r & 1023;
    sta32f(A.hbuf + ((l2*2+0)*BB + b)*HH + j, 0.f);
  }
  if (bid < 128){
    for (int t = tid; t < 3*32*8; t += 1024){
      int l2 = t/(32*8), r = t%(32*8), b = r>>3, jj = r&7;
      A.cbuf[((size_t)l2*BB + b)*HH + bid*8 + jj] = 0.f;
    }
  }
  gbar(A, ++nb);

  // P0: att1(0), att2(0), att3(0) at parity 0 (h=0 -> uniform softmax);
  //     prev(0) = x[:,T-1,:] into l0 plane parity 0.
  if (bid >= 128 && bid < 224){
    int l = (bid-128)>>5, b = (bid-128)&31;
    attend_phase(A, l, 0, b, sm);
  } else if (bid >= 224){
    int b = bid - 224;
    if (tid < 64){
      float v = A.x[((size_t)b*TT + (TT-1))*DIN + tid];
      u16 h = f2bf(v);
      // u16 stores into plane: pack pairwise via two lanes -> use u32 by even lane
      if ((tid & 1) == 0){
        float v1 = A.x[((size_t)b*TT + (TT-1))*DIN + tid + 1];
        u16 h1 = f2bf(v1);
        sta32((u32*)A.pl[0][0][0] + ((size_t)b*KP0 + 32 + tid)/2,
              (u32)h | ((u32)h1<<16));
        u16 l0 = f2bf(v - bf2f(h)), l1 = f2bf(v1 - bf2f(h1));
        sta32((u32*)A.pl[0][0][1] + ((size_t)b*KP0 + 32 + tid)/2,
              (u32)l0 | ((u32)l1<<16));
      }
    }
  }
  gbar(A, ++nb);

  for (int s = 0; s < NSTEP; ++s){
    const int p = s&1, pn = p^1;
    // P1: G1(s)
    if (bid < 128) gemm_phase<0,KP0,9>(A, p, pn, sm);
    gbar(A, ++nb);
    // P2: G2(s) || att1(s+1)
    if (bid < 128)        gemm_phase<1,KP12,17>(A, p, pn, sm);
    else if (bid < 160)   attend_phase(A, 0, pn, bid-128, sm);
    gbar(A, ++nb);
    // P3: G3(s) || att2(s+1)
    if (bid < 128)        gemm_phase<2,KP12,17>(A, p, pn, sm);
    else if (bid < 160)   attend_phase(A, 1, pn, bid-128, sm);
    gbar(A, ++nb);
    // P4: out(s) || att3(s+1)
    if (bid >= 128 && bid < 160)      out_phase(A, pn, s, bid-128, sm);
    else if (bid >= 160 && bid < 192) attend_phase(A, 2, pn, bid-160, sm);
    gbar(A, ++nb);
  }
}

// ---------------------------------------------------------------------------
extern "C" void kernel_launch(void* const* d_in, const int* in_sizes, int n_in,
                              void* d_out, int out_size, void* d_ws, size_t ws_size,
                              hipStream_t stream) {
  const float* x    = (const float*)d_in[0];
  const float* w_c1 = (const float*)d_in[1];
  const float* b_c1 = (const float*)d_in[2];
  const float* w_c2 = (const float*)d_in[3];
  const float* b_c2 = (const float*)d_in[4];
  const float* w_c3 = (const float*)d_in[5];
  const float* b_c3 = (const float*)d_in[6];

  SeqArgs A;
  A.x     = x;
  A.wa[0] = (const float*)d_in[7];
  A.wa[1] = (const float*)d_in[9];
  A.wa[2] = (const float*)d_in[11];
  const float* wih1 = (const float*)d_in[13];
  const float* whh1 = (const float*)d_in[14];
  const float* bih1 = (const float*)d_in[15];
  const float* bhh1 = (const float*)d_in[16];
  const float* wih2 = (const float*)d_in[17];
  const float* whh2 = (const float*)d_in[18];
  const float* bih2 = (const float*)d_in[19];
  const float* bhh2 = (const float*)d_in[20];
  const float* wih3 = (const float*)d_in[21];
  const float* whh3 = (const float*)d_in[22];
  const float* bih3 = (const float*)d_in[23];
  const float* bhh3 = (const float*)d_in[24];
  A.wout = (const float*)d_in[25];
  A.bout = (const float*)d_in[26];
  A.dout = (float*)d_out;

  char* base = (char*)d_ws;
  size_t off = 0;
  auto alloc = [&](size_t bytes)->char*{
    char* pp = base + off; off = (off + bytes + 255) & ~(size_t)255; return pp;
  };

  u16* enc = (u16*)alloc((size_t)BB*LL3*CC3*2);            // 4.14 MB
  A.enc  = enc;
  A.hbuf = (float*)alloc((size_t)3*2*BB*HH*4);             // 0.79 MB
  A.cbuf = (float*)alloc((size_t)3*BB*HH*4);               // 0.39 MB
  for (int l=0;l<3;++l){
    size_t kp = (l==0)? KP0 : KP12;
    for (int par=0; par<2; ++par)
      for (int hl=0; hl<2; ++hl)
        A.pl[l][par][hl] = (u16*)alloc((size_t)BB*kp*2);
  }
  float* bs0 = (float*)alloc(4096*4);
  float* bs1 = (float*)alloc(4096*4);
  float* bs2 = (float*)alloc(4096*4);
  A.bsum[0]=bs0; A.bsum[1]=bs1; A.bsum[2]=bs2;
  u32* bar = (u32*)alloc(4096);
  A.slots = bar;          // [0,256)
  A.go    = bar + 320;    // separate cache line
  u16 *wp[6];
  wp[0] = (u16*)alloc((size_t)4096*KP0*2);                 // 9.44 MB
  wp[1] = (u16*)alloc((size_t)4096*KP0*2);
  wp[2] = (u16*)alloc((size_t)4096*KP12*2);                // 17.8 MB
  wp[3] = (u16*)alloc((size_t)4096*KP12*2);
  wp[4] = (u16*)alloc((size_t)4096*KP12*2);
  wp[5] = (u16*)alloc((size_t)4096*KP12*2);
  A.wwh[0]=wp[0]; A.wwl[0]=wp[1];
  A.wwh[1]=wp[2]; A.wwl[1]=wp[3];
  A.wwh[2]=wp[4]; A.wwl[2]=wp[5];
  // total ~97 MB (R2 passed at this size)

  // conv temps alias the layer-1 hi weight buffer (preps run after convs)
  float* r1 = (float*)wp[0];                         // 2.09 MB
  float* r2 = (float*)(((char*)wp[0]) + 2095104);    // 4.17 MB (ends < 9.4 MB)

  conv1_kernel<<<(BB*LL1+255)/256, 256, 0, stream>>>(x, w_c1, b_c1, r1);
  conv2_kernel<<<(BB*LL2+255)/256, 256, 0, stream>>>(r1, w_c2, b_c2, r2);
  conv3_kernel<<<(BB*LL3+255)/256, 256, 0, stream>>>(r2, w_c3, b_c3, enc);
  prep_kernel<<<2048, 256, 0, stream>>>(wih1, whh1, wp[0], wp[1],   96, K0,  KP0);
  prep_kernel<<<2048, 256, 0, stream>>>(wih2, whh2, wp[2], wp[3], 1056, K12, KP12);
  prep_kernel<<<2048, 256, 0, stream>>>(wih3, whh3, wp[4], wp[5], 1056, K12, KP12);
  bsum_kernel<<<48, 256, 0, stream>>>(bih1,bhh1,bih2,bhh2,bih3,bhh3, bs0,bs1,bs2);
  barinit_kernel<<<1, 256, 0, stream>>>(bar);

  void* params[] = { (void*)&A };
  hipLaunchCooperativeKernel((const void*)seq_kernel, dim3(256), dim3(1024),
                             params, 0, stream);
}

// Round 8
// 9911.169 us; speedup vs baseline: 1.0238x; 1.0078x over previous
//
#include <hip/hip_runtime.h>

// ============================================================================
// Conv2Seq round 7: R6 + explicit 1-ahead register prefetch in the GEMM K-loop
// (double-buffered wh/wl/xh/xl, fully unrolled, 3 accumulators). R6 PMC showed
// VGPR=64 and ~6300 cyc/iteration => zero MLP; this restores load pipelining.
// Everything else identical to R6 (distributed-slot barrier, bypass atomics
// for mutable data, plain cached loads for immutable weights/enc).
// ============================================================================

#define BB   32
#define TT   2048
#define DIN  64
#define HH   1024
#define DOUT 64
#define NSTEP 60
#define LL1  2045
#define LL2  2038
#define LL3  2023
#define CC1  8
#define CC2  16
#define CC3  32
#define K0   1120     // layer1 real K: [ctx32 | prev64 | h1 1024]
#define K12  2080     // layers2/3 real K: [ctx32 | h_prev 1024 | h_own 1024]
#define KP0  1152     // padded (9 chunks of 128)
#define KP12 2176     // padded (17 chunks of 128)

typedef unsigned short u16;
typedef unsigned int   u32;
typedef unsigned long long u64;
typedef __attribute__((ext_vector_type(8))) short bf16x8;
typedef __attribute__((ext_vector_type(4))) float f32x4;

union FR { u64 q[2]; bf16x8 v; };

__device__ __forceinline__ float4 ld4(const float* p){ return *(const float4*)p; }
__device__ __forceinline__ u16 f2bf(float x){
  unsigned u = __float_as_uint(x);
  return (u16)((u + 0x7FFFu + ((u>>16)&1u)) >> 16);
}
__device__ __forceinline__ float bf2f(u16 h){ return __uint_as_float(((unsigned)h)<<16); }
__device__ __forceinline__ float bfq(u64 w, int i){
  return __uint_as_float(((u32)((w >> (16*i)) & 0xffffu)) << 16);
}
// coherent-point accessors (bypass stale L1/L2) for cross-block mutable data
__device__ __forceinline__ float lda32f(const float* p){
  return __hip_atomic_load(p, __ATOMIC_RELAXED, __HIP_MEMORY_SCOPE_AGENT);
}
__device__ __forceinline__ u32 lda32u(const u32* p){
  return __hip_atomic_load(p, __ATOMIC_RELAXED, __HIP_MEMORY_SCOPE_AGENT);
}
__device__ __forceinline__ u64 lda64(const void* p){
  return __hip_atomic_load((const u64*)p, __ATOMIC_RELAXED, __HIP_MEMORY_SCOPE_AGENT);
}
__device__ __forceinline__ void sta32(u32* p, u32 v){
  __hip_atomic_store(p, v, __ATOMIC_RELAXED, __HIP_MEMORY_SCOPE_AGENT);
}
__device__ __forceinline__ void sta32f(float* p, float v){
  __hip_atomic_store(p, v, __ATOMIC_RELAXED, __HIP_MEMORY_SCOPE_AGENT);
}

// ---------------------------------------------------------------------------
// conv kernels (one-shot; conv3 emits bf16 enc)
// ---------------------------------------------------------------------------
__global__ __launch_bounds__(256) void conv1_kernel(const float* __restrict__ x,
    const float* __restrict__ w, const float* __restrict__ bias,
    float* __restrict__ out){
  int idx = blockIdx.x*256 + threadIdx.x;
  if (idx >= BB*LL1) return;
  int b = idx / LL1, t = idx % LL1;
  float acc[CC1];
  #pragma unroll
  for (int c=0;c<CC1;++c) acc[c] = bias[c];
  for (int k=0;k<4;++k){
    const float* xr = x + ((size_t)(b*TT + t + k))*DIN;
    for (int d=0; d<DIN; d+=4){
      float4 v = ld4(xr + d);
      #pragma unroll
      for (int c=0;c<CC1;++c){
        acc[c] += v.x * w[((c*DIN+d  )<<2)+k]
                + v.y * w[((c*DIN+d+1)<<2)+k]
                + v.z * w[((c*DIN+d+2)<<2)+k]
                + v.w * w[((c*DIN+d+3)<<2)+k];
      }
    }
  }
  float* o = out + (size_t)idx*CC1;
  #pragma unroll
  for (int c=0;c<CC1;++c) o[c] = fmaxf(acc[c], 0.f);
}

__global__ __launch_bounds__(256) void conv2_kernel(const float* __restrict__ r1,
    const float* __restrict__ w, const float* __restrict__ bias,
    float* __restrict__ out){
  int idx = blockIdx.x*256 + threadIdx.x;
  if (idx >= BB*LL2) return;
  int b = idx / LL2, t = idx % LL2;
  float acc[CC2];
  #pragma unroll
  for (int c=0;c<CC2;++c) acc[c] = bias[c];
  for (int k=0;k<8;++k){
    const float* rr = r1 + ((size_t)(b*LL1 + t + k))*CC1;
    for (int c1=0;c1<CC1;c1+=4){
      float4 v = ld4(rr + c1);
      #pragma unroll
      for (int c=0;c<CC2;++c){
        acc[c] += v.x * w[((c*CC1+c1  )<<3)+k]
                + v.y * w[((c*CC1+c1+1)<<3)+k]
                + v.z * w[((c*CC1+c1+2)<<3)+k]
                + v.w * w[((c*CC1+c1+3)<<3)+k];
      }
    }
  }
  float* o = out + (size_t)idx*CC2;
  #pragma unroll
  for (int c=0;c<CC2;++c) o[c] = fmaxf(acc[c], 0.f);
}

__global__ __launch_bounds__(256) void conv3_kernel(const float* __restrict__ r2,
    const float* __restrict__ w, const float* __restrict__ bias,
    u16* __restrict__ out){
  int idx = blockIdx.x*256 + threadIdx.x;
  if (idx >= BB*LL3) return;
  int b = idx / LL3, t = idx % LL3;
  float acc[CC3];
  #pragma unroll
  for (int c=0;c<CC3;++c) acc[c] = bias[c];
  for (int k=0;k<16;++k){
    const float* rr = r2 + ((size_t)(b*LL2 + t + k))*CC2;
    for (int c2=0;c2<CC2;c2+=4){
      float4 v = ld4(rr + c2);
      #pragma unroll
      for (int c=0;c<CC3;++c){
        acc[c] += v.x * w[((c*CC2+c2  )<<4)+k]
                + v.y * w[((c*CC2+c2+1)<<4)+k]
                + v.z * w[((c*CC2+c2+2)<<4)+k]
                + v.w * w[((c*CC2+c2+3)<<4)+k];
      }
    }
  }
  u16* o = out + (size_t)idx*CC3;
  #pragma unroll
  for (int c=0;c<CC3;++c) o[c] = f2bf(fmaxf(acc[c], 0.f));
}

// ---------------------------------------------------------------------------
// weight prep: row reorder rblk = bid*32 + rl, rl = gate*8+jj,
// grow = gate*1024 + bid*8 + jj. K-order: [wih (Kih)] ++ [whh (1024)] ++ pad0.
// hi/lo bf16 split. Row stride = padded KP.
// ---------------------------------------------------------------------------
__global__ __launch_bounds__(256) void prep_kernel(const float* __restrict__ wih,
    const float* __restrict__ whh, u16* __restrict__ wh, u16* __restrict__ wl,
    int Kih, int Kin, int KPp){
  const size_t total = (size_t)4096*KPp;
  for (size_t idx = (size_t)blockIdx.x*256 + threadIdx.x; idx < total;
       idx += (size_t)gridDim.x*256){
    int rblk = idx / KPp, k = idx - (size_t)rblk*KPp;
    int bid = rblk>>5, rl = rblk&31, g = rl>>3, jj = rl&7;
    int grow = g*1024 + bid*8 + jj;
    float v = 0.f;
    if (k < Kih)      v = wih[(size_t)grow*Kih + k];
    else if (k < Kin) v = whh[(size_t)grow*HH + (k-Kih)];
    u16 h = f2bf(v);
    wh[idx] = h;
    wl[idx] = f2bf(v - bf2f(h));
  }
}

__global__ __launch_bounds__(256) void bsum_kernel(
    const float* __restrict__ bih1, const float* __restrict__ bhh1,
    const float* __restrict__ bih2, const float* __restrict__ bhh2,
    const float* __restrict__ bih3, const float* __restrict__ bhh3,
    float* __restrict__ bs0, float* __restrict__ bs1, float* __restrict__ bs2){
  int idx = blockIdx.x*256 + threadIdx.x;
  if (idx < 4096)       bs0[idx] = bih1[idx] + bhh1[idx];
  else if (idx < 8192){ int r=idx-4096; bs1[r] = bih2[r] + bhh2[r]; }
  else if (idx < 12288){int r=idx-8192; bs2[r] = bih3[r] + bhh3[r]; }
}

__global__ void barinit_kernel(u32* bar){
  for (int i = threadIdx.x; i < 512; i += 256) bar[i] = 0u;
}

// ---------------------------------------------------------------------------
// Persistent sequence kernel
// ---------------------------------------------------------------------------
struct SeqArgs {
  const float *x;
  const float *wa[3];
  const float *wout, *bout;
  const u16 *enc;              // [32][2023][32] bf16 (immutable)
  const u16 *wwh[3], *wwl[3];  // immutable, padded rows
  const float *bsum[3];        // immutable
  u16 *pl[3][2][2];            // [layer][parity][hi/lo], row stride KP
  float *hbuf;                 // [3][2][32][1024]  (mutable, shared)
  float *cbuf;                 // [3][32][1024] (block-private)
  float *dout;                 // [32][60][64]
  u32 *slots;                  // [256] arrival epochs
  u32 *go;                     // release word
};

#define SMEM_FLOATS 5376

// distributed-slot grid barrier; no fences except RELEASE on the slot store.
__device__ __forceinline__ void gbar(const SeqArgs& A, u32 nb){
  asm volatile("s_waitcnt vmcnt(0)" ::: "memory");
  __syncthreads();
  const int bid = blockIdx.x, tid = threadIdx.x;
  if (tid == 0)
    __hip_atomic_store(A.slots + bid, nb, __ATOMIC_RELEASE,
                       __HIP_MEMORY_SCOPE_AGENT);
  if (bid == 0){
    if (tid < 64){
      for (;;){
        u32 v0 = lda32u(A.slots + tid);
        u32 v1 = lda32u(A.slots + 64 + tid);
        u32 v2 = lda32u(A.slots + 128 + tid);
        u32 v3 = lda32u(A.slots + 192 + tid);
        u32 mn = min(min(v0,v1), min(v2,v3));
        if (__all(mn >= nb)) break;
        __builtin_amdgcn_s_sleep(4);
      }
      if (tid == 0) sta32(A.go, nb);
    }
  } else if (tid == 0){
    while (lda32u(A.go) < nb) __builtin_amdgcn_s_sleep(4);
  }
  __syncthreads();
}

// attend for (l,b) parity par: q = wa^T h ; softmax(enc.q) ; ctx -> plane
__device__ void attend_phase(const SeqArgs& A, int l, int par, int b, float* sm){
  const int tid = threadIdx.x;
  const float* wa = A.wa[l];
  const float* h  = A.hbuf + (size_t)((l*2+par)*BB + b)*HH;
  const int strU = ((l==0)? KP0 : KP12) >> 1;   // u32 row stride
  u16* ch = A.pl[l][par][0];
  u16* cl = A.pl[l][par][1];
  float* sh  = sm;          // 1024
  float* sq  = sm + 1024;   // 32
  float* ss  = sm + 1056;   // 2023 (pad 2048)
  float* red = sm + 3104;   // 1024
  float* ctxf= sm + 4128;   // 32

  sh[tid] = lda32f(h + tid);
  __syncthreads();

  const int cc = tid&31, g = tid>>5;
  float part = 0.f;
  for (int kk=g; kk<HH; kk+=32) part += wa[kk*32+cc]*sh[kk];
  red[tid] = part; __syncthreads();
  if (tid<32){ float s=0.f;
    #pragma unroll
    for (int gg=0; gg<32; ++gg) s += red[gg*32+tid];
    sq[tid]=s; }
  __syncthreads();

  const u16* eb = A.enc + (size_t)b*LL3*CC3;
  float lmax = -1e30f;
  for (int t=tid; t<LL3; t+=1024){
    const u16* er = eb + t*32; float dot=0.f;
    #pragma unroll
    for (int c4=0;c4<8;++c4){
      u64 w = *(const u64*)(er + c4*4);
      dot += bfq(w,0)*sq[c4*4] + bfq(w,1)*sq[c4*4+1]
           + bfq(w,2)*sq[c4*4+2] + bfq(w,3)*sq[c4*4+3];
    }
    ss[t]=dot; lmax=fmaxf(lmax,dot);
  }
  #pragma unroll
  for (int o=32;o>0;o>>=1) lmax = fmaxf(lmax, __shfl_xor(lmax,o));
  if ((tid&63)==0) red[tid>>6] = lmax;
  __syncthreads();
  if (tid==0){ float m=red[0]; for (int w=1;w<16;++w) m=fmaxf(m,red[w]); red[16]=m; }
  __syncthreads();
  const float m = red[16];

  float lsum = 0.f;
  for (int t=tid; t<LL3; t+=1024){ float e=__expf(ss[t]-m); ss[t]=e; lsum+=e; }
  #pragma unroll
  for (int o=32;o>0;o>>=1) lsum += __shfl_xor(lsum,o);
  if ((tid&63)==0) red[32 + (tid>>6)] = lsum;
  __syncthreads();
  if (tid==0){ float z=0.f; for (int w=0;w<16;++w) z+=red[32+w]; red[17]=1.0f/z; }
  __syncthreads();
  const float rZ = red[17];

  float acc = 0.f;
  for (int t=g; t<LL3; t+=32) acc += ss[t]*bf2f(eb[t*32+cc]);
  __syncthreads();
  red[tid] = acc; __syncthreads();
  if (tid<32){ float s=0.f;
    #pragma unroll
    for (int gg=0; gg<32; ++gg) s += red[gg*32+tid];
    ctxf[tid] = s*rZ; }
  __syncthreads();
  if (tid < 16){
    float v0=ctxf[2*tid], v1=ctxf[2*tid+1];
    sta32((u32*)ch + (size_t)b*strU + tid, (u32)f2bf(v0) | ((u32)f2bf(v1)<<16));
  } else if (tid < 32){
    int t2 = tid-16;
    float v0=ctxf[2*t2], v1=ctxf[2*t2+1];
    u16 h0=f2bf(v0), h1=f2bf(v1);
    sta32((u32*)cl + (size_t)b*strU + t2,
          (u32)f2bf(v0-bf2f(h0)) | ((u32)f2bf(v1-bf2f(h1))<<16));
  }
}

// out phase: y(s) = h3(pn) @ wout^T + bout -> dout[:,s,:] and prev slot of
// layer-1 plane parity pn (consumed by G1(s+1)).
__device__ void out_phase(const SeqArgs& A, int pn, int s, int b, float* sm){
  float* sh = sm; float* red = sm+1024; float* yv = sm+2048;
  const int tid = threadIdx.x;
  sh[tid] = lda32f(A.hbuf + (size_t)((2*2+pn)*BB + b)*HH + tid);
  __syncthreads();
  const int d = tid&63, kg = tid>>6;
  const float* wr = A.wout + (size_t)d*HH + kg*64;
  const float* hh = sh + kg*64;
  float acc = 0.f;
  #pragma unroll
  for (int k=0;k<64;k+=4){ float4 w4=ld4(wr+k); float4 hv=*(const float4*)&hh[k];
    acc += w4.x*hv.x+w4.y*hv.y+w4.z*hv.z+w4.w*hv.w; }
  red[tid]=acc; __syncthreads();
  if (tid<64){
    float y = A.bout[tid];
    #pragma unroll
    for (int kk=0;kk<16;++kk) y += red[kk*64+tid];
    A.dout[((size_t)b*NSTEP+s)*DOUT+tid] = y;
    yv[tid] = y;
  }
  __syncthreads();
  if (tid < 32){
    float v0=yv[2*tid], v1=yv[2*tid+1];
    sta32((u32*)A.pl[0][pn][0] + (size_t)b*(KP0>>1) + 16 + tid,
          (u32)f2bf(v0) | ((u32)f2bf(v1)<<16));
  } else if (tid < 64){
    int t2 = tid-32;
    float v0=yv[2*t2], v1=yv[2*t2+1];
    u16 h0=f2bf(v0), h1=f2bf(v1);
    sta32((u32*)A.pl[0][pn][1] + (size_t)b*(KP0>>1) + 16 + t2,
          (u32)f2bf(v0-bf2f(h0)) | ((u32)f2bf(v1-bf2f(h1))<<16));
  }
}

// MFMA GEMM (32 weight rows x 32 batch per block, 128 blocks) + fused cell.
// Explicit 1-ahead prefetch: double-buffered {wh,wl,xh,xl}, loads of chunk
// it+1 issued before the MFMAs of chunk it; fully unrolled; 3 accumulators.
template<int L, int KPL, int NIT>
__device__ void gemm_phase(const SeqArgs& A, int p, int pn, float* sm){
  const int bid = blockIdx.x, tid = threadIdx.x;
  const u16* wh  = A.wwh[L];
  const u16* wlo = A.wwl[L];
  const u16* ih = A.pl[L][p][0];
  const u16* il = A.pl[L][p][1];
  const int wave = tid>>6, lane = tid&63;
  const int wt = wave>>3, xh = (wave>>2)&1, kq = wave&3;
  const int r15 = lane&15, g8 = (lane>>4)<<3;
  const u16* wph = wh  + (size_t)(bid*32 + wt*16 + r15)*KPL + g8 + kq*32;
  const u16* wpl = wlo + (size_t)(bid*32 + wt*16 + r15)*KPL + g8 + kq*32;
  const u16* xb  = ih + (size_t)(xh*16 + r15)*KPL + g8 + kq*32;
  const u16* xlb = il + (size_t)(xh*16 + r15)*KPL + g8 + kq*32;

  f32x4 acc0 = {0.f,0.f,0.f,0.f}, acc1 = {0.f,0.f,0.f,0.f}, acc2 = {0.f,0.f,0.f,0.f};
  bf16x8 whA, wlA, whB, wlB;
  FR xhA, xlA, xhB, xlB;
  // prologue: chunk 0 -> A buffers
  whA = *(const bf16x8*)(wph);
  wlA = *(const bf16x8*)(wpl);
  xhA.q[0] = lda64(xb);    xhA.q[1] = lda64(xb+4);
  xlA.q[0] = lda64(xlb);   xlA.q[1] = lda64(xlb+4);
  #pragma unroll
  for (int it = 0; it < NIT; ++it){
    const int o = (it+1)*128;
    if ((it & 1) == 0){
      if (it+1 < NIT){
        whB = *(const bf16x8*)(wph + o);
        wlB = *(const bf16x8*)(wpl + o);
        xhB.q[0] = lda64(xb+o);  xhB.q[1] = lda64(xb+o+4);
        xlB.q[0] = lda64(xlb+o); xlB.q[1] = lda64(xlb+o+4);
      }
      acc0 = __builtin_amdgcn_mfma_f32_16x16x32_bf16(xhA.v, whA, acc0, 0,0,0);
      acc1 = __builtin_amdgcn_mfma_f32_16x16x32_bf16(xlA.v, whA, acc1, 0,0,0);
      acc2 = __builtin_amdgcn_mfma_f32_16x16x32_bf16(xhA.v, wlA, acc2, 0,0,0);
    } else {
      if (it+1 < NIT){
        whA = *(const bf16x8*)(wph + o);
        wlA = *(const bf16x8*)(wpl + o);
        xhA.q[0] = lda64(xb+o);  xhA.q[1] = lda64(xb+o+4);
        xlA.q[0] = lda64(xlb+o); xlA.q[1] = lda64(xlb+o+4);
      }
      acc0 = __builtin_amdgcn_mfma_f32_16x16x32_bf16(xhB.v, whB, acc0, 0,0,0);
      acc1 = __builtin_amdgcn_mfma_f32_16x16x32_bf16(xlB.v, whB, acc1, 0,0,0);
      acc2 = __builtin_amdgcn_mfma_f32_16x16x32_bf16(xhB.v, wlB, acc2, 0,0,0);
    }
  }
  f32x4 acc = acc0 + acc1 + acc2;

  float* red = sm;            // 16*256
  float* sg  = sm + 4096;     // 32*32
  float* hv  = sm + 5120;     // 8*32
  #pragma unroll
  for (int rg=0; rg<4; ++rg) red[wave*256 + lane*4 + rg] = acc[rg];
  __syncthreads();
  {
    const int tile = tid>>8, e = tid&255;
    const int wt2 = tile>>1, xh2 = tile&1;
    const int base = (wt2*8 + xh2*4)*256 + e;
    float v = red[base] + red[base+256] + red[base+512] + red[base+768];
    const int ln = e>>2, rg = e&3;
    // D layout (m89): col=lane&15 -> weight row, row=4*(lane>>4)+reg -> batch
    sg[(wt2*16 + (ln&15))*32 + xh2*16 + ((ln>>4)<<2) + rg] = v;
  }
  __syncthreads();
  if (tid < 256){
    const int b = tid&31, jj = tid>>5;
    const int j = bid*8 + jj;
    const float* bs = A.bsum[L];
    float gi = sg[(0 +jj)*32+b] + bs[j];
    float gf = sg[(8 +jj)*32+b] + bs[1024+j];
    float gg = sg[(16+jj)*32+b] + bs[2048+j];
    float go = sg[(24+jj)*32+b] + bs[3072+j];
    float i_ = 1.f/(1.f+__expf(-gi));
    float f_ = 1.f/(1.f+__expf(-gf));
    float g_ = tanhf(gg);
    float o_ = 1.f/(1.f+__expf(-go));
    float* cb = A.cbuf + ((size_t)L*BB + b)*HH + j;
    float c = f_*cb[0] + i_*g_;
    cb[0] = c;
    float hval = o_*tanhf(c);
    sta32f(A.hbuf + ((size_t)(L*2+pn)*BB + b)*HH + j, hval);
    hv[jj*32 + b] = hval;
  }
  __syncthreads();
  if (tid < 128){
    const int b = tid&31, pr = tid>>5;
    const int jj0 = pr*2;
    float v0 = hv[jj0*32+b], v1 = hv[(jj0+1)*32+b];
    u16 h0 = f2bf(v0), h1 = f2bf(v1);
    u32 ph  = (u32)h0 | ((u32)h1<<16);
    u32 plq = (u32)f2bf(v0-bf2f(h0)) | ((u32)f2bf(v1-bf2f(h1))<<16);
    const int col = bid*8 + jj0;
    if (L == 0){
      size_t i1 = ((size_t)b*KP0  + 96   + col) >> 1;   // own h1, next step
      sta32((u32*)A.pl[0][pn][0] + i1, ph);  sta32((u32*)A.pl[0][pn][1] + i1, plq);
      size_t i2 = ((size_t)b*KP12 + 32   + col) >> 1;   // L2 input, this step
      sta32((u32*)A.pl[1][p ][0] + i2, ph);  sta32((u32*)A.pl[1][p ][1] + i2, plq);
    } else if (L == 1){
      size_t i1 = ((size_t)b*KP12 + 1056 + col) >> 1;   // own h2, next step
      sta32((u32*)A.pl[1][pn][0] + i1, ph);  sta32((u32*)A.pl[1][pn][1] + i1, plq);
      size_t i2 = ((size_t)b*KP12 + 32   + col) >> 1;   // L3 input, this step
      sta32((u32*)A.pl[2][p ][0] + i2, ph);  sta32((u32*)A.pl[2][p ][1] + i2, plq);
    } else {
      size_t i1 = ((size_t)b*KP12 + 1056 + col) >> 1;   // own h3, next step
      sta32((u32*)A.pl[2][pn][0] + i1, ph);  sta32((u32*)A.pl[2][pn][1] + i1, plq);
    }
  }
}

__global__ __launch_bounds__(1024, 4) void seq_kernel(SeqArgs A){
  __shared__ float sm[SMEM_FLOATS];
  const int bid = blockIdx.x, tid = threadIdx.x;
  const size_t gid = (size_t)bid*1024 + tid;
  const size_t gstr = (size_t)256*1024;
  u32 nb = 0;

  // ---- init: zero ALL planes (both parities, hi/lo, incl pads), hbuf par0,
  //      cbuf (block-private). prev/ctx filled in P0 after the barrier. ----
  {
    const size_t n0 = (size_t)32*(KP0>>1);      // u32 per l0 buffer
    const size_t n1 = (size_t)32*(KP12>>1);     // u32 per l1/l2 buffer
    for (size_t i = gid; i < n0; i += gstr){
      #pragma unroll
      for (int q=0;q<2;++q)
        #pragma unroll
        for (int hl=0;hl<2;++hl)
          sta32((u32*)A.pl[0][q][hl] + i, 0u);
    }
    for (size_t i = gid; i < n1; i += gstr){
      #pragma unroll
      for (int q=0;q<2;++q)
        #pragma unroll
        for (int hl=0;hl<2;++hl){
          sta32((u32*)A.pl[1][q][hl] + i, 0u);
          sta32((u32*)A.pl[2][q][hl] + i, 0u);
        }
    }
  }
  for (size_t i = gid; i < (size_t)3*32*1024; i += gstr){
    size_t l2 = i >> 15, r = i & 32767, b = r >> 10, j = r & 1023;
    sta32f(A.hbuf + ((l2*2+0)*BB + b)*HH + j, 0.f);
  }
  if (bid < 128){
    for (int t = tid; t < 3*32*8; t += 1024){
      int l2 = t/(32*8), r = t%(32*8), b = r>>3, jj = r&7;
      A.cbuf[((size_t)l2*BB + b)*HH + bid*8 + jj] = 0.f;
    }
  }
  gbar(A, ++nb);

  // P0: att1(0), att2(0), att3(0) at parity 0 (h=0 -> uniform softmax);
  //     prev(0) = x[:,T-1,:] into l0 plane parity 0.
  if (bid >= 128 && bid < 224){
    int l = (bid-128)>>5, b = (bid-128)&31;
    attend_phase(A, l, 0, b, sm);
  } else if (bid >= 224){
    int b = bid - 224;
    if (tid < 64){
      float v = A.x[((size_t)b*TT + (TT-1))*DIN + tid];
      u16 h = f2bf(v);
      if ((tid & 1) == 0){
        float v1 = A.x[((size_t)b*TT + (TT-1))*DIN + tid + 1];
        u16 h1 = f2bf(v1);
        sta32((u32*)A.pl[0][0][0] + ((size_t)b*KP0 + 32 + tid)/2,
              (u32)h | ((u32)h1<<16));
        u16 l0 = f2bf(v - bf2f(h)), l1 = f2bf(v1 - bf2f(h1));
        sta32((u32*)A.pl[0][0][1] + ((size_t)b*KP0 + 32 + tid)/2,
              (u32)l0 | ((u32)l1<<16));
      }
    }
  }
  gbar(A, ++nb);

  for (int s = 0; s < NSTEP; ++s){
    const int p = s&1, pn = p^1;
    // P1: G1(s)
    if (bid < 128) gemm_phase<0,KP0,9>(A, p, pn, sm);
    gbar(A, ++nb);
    // P2: G2(s) || att1(s+1)
    if (bid < 128)        gemm_phase<1,KP12,17>(A, p, pn, sm);
    else if (bid < 160)   attend_phase(A, 0, pn, bid-128, sm);
    gbar(A, ++nb);
    // P3: G3(s) || att2(s+1)
    if (bid < 128)        gemm_phase<2,KP12,17>(A, p, pn, sm);
    else if (bid < 160)   attend_phase(A, 1, pn, bid-128, sm);
    gbar(A, ++nb);
    // P4: out(s) || att3(s+1)
    if (bid >= 128 && bid < 160)      out_phase(A, pn, s, bid-128, sm);
    else if (bid >= 160 && bid < 192) attend_phase(A, 2, pn, bid-160, sm);
    gbar(A, ++nb);
  }
}

// ---------------------------------------------------------------------------
extern "C" void kernel_launch(void* const* d_in, const int* in_sizes, int n_in,
                              void* d_out, int out_size, void* d_ws, size_t ws_size,
                              hipStream_t stream) {
  const float* x    = (const float*)d_in[0];
  const float* w_c1 = (const float*)d_in[1];
  const float* b_c1 = (const float*)d_in[2];
  const float* w_c2 = (const float*)d_in[3];
  const float* b_c2 = (const float*)d_in[4];
  const float* w_c3 = (const float*)d_in[5];
  const float* b_c3 = (const float*)d_in[6];

  SeqArgs A;
  A.x     = x;
  A.wa[0] = (const float*)d_in[7];
  A.wa[1] = (const float*)d_in[9];
  A.wa[2] = (const float*)d_in[11];
  const float* wih1 = (const float*)d_in[13];
  const float* whh1 = (const float*)d_in[14];
  const float* bih1 = (const float*)d_in[15];
  const float* bhh1 = (const float*)d_in[16];
  const float* wih2 = (const float*)d_in[17];
  const float* whh2 = (const float*)d_in[18];
  const float* bih2 = (const float*)d_in[19];
  const float* bhh2 = (const float*)d_in[20];
  const float* wih3 = (const float*)d_in[21];
  const float* whh3 = (const float*)d_in[22];
  const float* bih3 = (const float*)d_in[23];
  const float* bhh3 = (const float*)d_in[24];
  A.wout = (const float*)d_in[25];
  A.bout = (const float*)d_in[26];
  A.dout = (float*)d_out;

  char* base = (char*)d_ws;
  size_t off = 0;
  auto alloc = [&](size_t bytes)->char*{
    char* pp = base + off; off = (off + bytes + 255) & ~(size_t)255; return pp;
  };

  u16* enc = (u16*)alloc((size_t)BB*LL3*CC3*2);            // 4.14 MB
  A.enc  = enc;
  A.hbuf = (float*)alloc((size_t)3*2*BB*HH*4);             // 0.79 MB
  A.cbuf = (float*)alloc((size_t)3*BB*HH*4);               // 0.39 MB
  for (int l=0;l<3;++l){
    size_t kp = (l==0)? KP0 : KP12;
    for (int par=0; par<2; ++par)
      for (int hl=0; hl<2; ++hl)
        A.pl[l][par][hl] = (u16*)alloc((size_t)BB*kp*2);
  }
  float* bs0 = (float*)alloc(4096*4);
  float* bs1 = (float*)alloc(4096*4);
  float* bs2 = (float*)alloc(4096*4);
  A.bsum[0]=bs0; A.bsum[1]=bs1; A.bsum[2]=bs2;
  u32* bar = (u32*)alloc(4096);
  A.slots = bar;          // [0,256)
  A.go    = bar + 320;    // separate cache line
  u16 *wp[6];
  wp[0] = (u16*)alloc((size_t)4096*KP0*2);                 // 9.44 MB
  wp[1] = (u16*)alloc((size_t)4096*KP0*2);
  wp[2] = (u16*)alloc((size_t)4096*KP12*2);                // 17.8 MB
  wp[3] = (u16*)alloc((size_t)4096*KP12*2);
  wp[4] = (u16*)alloc((size_t)4096*KP12*2);
  wp[5] = (u16*)alloc((size_t)4096*KP12*2);
  A.wwh[0]=wp[0]; A.wwl[0]=wp[1];
  A.wwh[1]=wp[2]; A.wwl[1]=wp[3];
  A.wwh[2]=wp[4]; A.wwl[2]=wp[5];
  // total ~97 MB (proven size)

  // conv temps alias the layer-1 hi weight buffer (preps run after convs)
  float* r1 = (float*)wp[0];                         // 2.09 MB
  float* r2 = (float*)(((char*)wp[0]) + 2095104);    // 4.17 MB (ends < 9.4 MB)

  conv1_kernel<<<(BB*LL1+255)/256, 256, 0, stream>>>(x, w_c1, b_c1, r1);
  conv2_kernel<<<(BB*LL2+255)/256, 256, 0, stream>>>(r1, w_c2, b_c2, r2);
  conv3_kernel<<<(BB*LL3+255)/256, 256, 0, stream>>>(r2, w_c3, b_c3, enc);
  prep_kernel<<<2048, 256, 0, stream>>>(wih1, whh1, wp[0], wp[1],   96, K0,  KP0);
  prep_kernel<<<2048, 256, 0, stream>>>(wih2, whh2, wp[2], wp[3], 1056, K12, KP12);
  prep_kernel<<<2048, 256, 0, stream>>>(wih3, whh3, wp[4], wp[5], 1056, K12, KP12);
  bsum_kernel<<<48, 256, 0, stream>>>(bih1,bhh1,bih2,bhh2,bih3,bhh3, bs0,bs1,bs2);
  barinit_kernel<<<1, 256, 0, stream>>>(bar);

  void* params[] = { (void*)&A };
  hipLaunchCooperativeKernel((const void*)seq_kernel, dim3(256), dim3(1024),
                             params, 0, stream);
}

// Round 9
// 7114.273 us; speedup vs baseline: 1.4263x; 1.3931x over previous
//
#include <hip/hip_runtime.h>

// ============================================================================
// Conv2Seq round 8: R7 structure + FRAGMENT-MAJOR layouts.
// Weights pre-gathered by prep so each wave streams CONTIGUOUS 1KB/iter
// (was: 16-row gather at 4.3KB lane stride -> ~540 GB/s; R2's coalesced
// staging hit ~925 GB/s with 2x the bytes). x planes scattered by producers
// into the same fragment-major form. Schedule/barrier/epilogue unchanged.
// ============================================================================

#define BB   32
#define TT   2048
#define DIN  64
#define HH   1024
#define DOUT 64
#define NSTEP 60
#define LL1  2045
#define LL2  2038
#define LL3  2023
#define CC1  8
#define CC2  16
#define CC3  32
#define K0   1120
#define K12  2080
#define KP0  1152     // 9 chunks of 128
#define KP12 2176     // 17 chunks of 128
#define NIT0  9
#define NIT12 17

typedef unsigned short u16;
typedef unsigned int   u32;
typedef unsigned long long u64;
typedef __attribute__((ext_vector_type(8))) short bf16x8;
typedef __attribute__((ext_vector_type(4))) float f32x4;

union FR { u64 q[2]; bf16x8 v; };

__device__ __forceinline__ float4 ld4(const float* p){ return *(const float4*)p; }
__device__ __forceinline__ u16 f2bf(float x){
  unsigned u = __float_as_uint(x);
  return (u16)((u + 0x7FFFu + ((u>>16)&1u)) >> 16);
}
__device__ __forceinline__ float bf2f(u16 h){ return __uint_as_float(((unsigned)h)<<16); }
__device__ __forceinline__ float bfq(u64 w, int i){
  return __uint_as_float(((u32)((w >> (16*i)) & 0xffffu)) << 16);
}
__device__ __forceinline__ float lda32f(const float* p){
  return __hip_atomic_load(p, __ATOMIC_RELAXED, __HIP_MEMORY_SCOPE_AGENT);
}
__device__ __forceinline__ u32 lda32u(const u32* p){
  return __hip_atomic_load(p, __ATOMIC_RELAXED, __HIP_MEMORY_SCOPE_AGENT);
}
__device__ __forceinline__ u64 lda64(const void* p){
  return __hip_atomic_load((const u64*)p, __ATOMIC_RELAXED, __HIP_MEMORY_SCOPE_AGENT);
}
__device__ __forceinline__ void sta32(u32* p, u32 v){
  __hip_atomic_store(p, v, __ATOMIC_RELAXED, __HIP_MEMORY_SCOPE_AGENT);
}
__device__ __forceinline__ void sta32f(float* p, float v){
  __hip_atomic_store(p, v, __ATOMIC_RELAXED, __HIP_MEMORY_SCOPE_AGENT);
}

// u32 slot index of pair (b, k) [k even] in a fragment-major x plane.
// entry F = (((xh*4+kq)*NIT + it)*64 + q*16 + r), 4 u32 per entry.
__device__ __forceinline__ u32 xidx(int NIT, int b, int k){
  int r = b & 15, xh = b >> 4;
  int it = k >> 7, kq = (k >> 5) & 3, q = (k >> 3) & 3, e = k & 7;
  return (u32)(((((xh*4 + kq)*NIT + it)*64) + q*16 + r)*4 + (e >> 1));
}

// ---------------------------------------------------------------------------
// conv kernels (one-shot; conv3 emits bf16 enc)
// ---------------------------------------------------------------------------
__global__ __launch_bounds__(256) void conv1_kernel(const float* __restrict__ x,
    const float* __restrict__ w, const float* __restrict__ bias,
    float* __restrict__ out){
  int idx = blockIdx.x*256 + threadIdx.x;
  if (idx >= BB*LL1) return;
  int b = idx / LL1, t = idx % LL1;
  float acc[CC1];
  #pragma unroll
  for (int c=0;c<CC1;++c) acc[c] = bias[c];
  for (int k=0;k<4;++k){
    const float* xr = x + ((size_t)(b*TT + t + k))*DIN;
    for (int d=0; d<DIN; d+=4){
      float4 v = ld4(xr + d);
      #pragma unroll
      for (int c=0;c<CC1;++c){
        acc[c] += v.x * w[((c*DIN+d  )<<2)+k]
                + v.y * w[((c*DIN+d+1)<<2)+k]
                + v.z * w[((c*DIN+d+2)<<2)+k]
                + v.w * w[((c*DIN+d+3)<<2)+k];
      }
    }
  }
  float* o = out + (size_t)idx*CC1;
  #pragma unroll
  for (int c=0;c<CC1;++c) o[c] = fmaxf(acc[c], 0.f);
}

__global__ __launch_bounds__(256) void conv2_kernel(const float* __restrict__ r1,
    const float* __restrict__ w, const float* __restrict__ bias,
    float* __restrict__ out){
  int idx = blockIdx.x*256 + threadIdx.x;
  if (idx >= BB*LL2) return;
  int b = idx / LL2, t = idx % LL2;
  float acc[CC2];
  #pragma unroll
  for (int c=0;c<CC2;++c) acc[c] = bias[c];
  for (int k=0;k<8;++k){
    const float* rr = r1 + ((size_t)(b*LL1 + t + k))*CC1;
    for (int c1=0;c1<CC1;c1+=4){
      float4 v = ld4(rr + c1);
      #pragma unroll
      for (int c=0;c<CC2;++c){
        acc[c] += v.x * w[((c*CC1+c1  )<<3)+k]
                + v.y * w[((c*CC1+c1+1)<<3)+k]
                + v.z * w[((c*CC1+c1+2)<<3)+k]
                + v.w * w[((c*CC1+c1+3)<<3)+k];
      }
    }
  }
  float* o = out + (size_t)idx*CC2;
  #pragma unroll
  for (int c=0;c<CC2;++c) o[c] = fmaxf(acc[c], 0.f);
}

__global__ __launch_bounds__(256) void conv3_kernel(const float* __restrict__ r2,
    const float* __restrict__ w, const float* __restrict__ bias,
    u16* __restrict__ out){
  int idx = blockIdx.x*256 + threadIdx.x;
  if (idx >= BB*LL3) return;
  int b = idx / LL3, t = idx % LL3;
  float acc[CC3];
  #pragma unroll
  for (int c=0;c<CC3;++c) acc[c] = bias[c];
  for (int k=0;k<16;++k){
    const float* rr = r2 + ((size_t)(b*LL2 + t + k))*CC2;
    for (int c2=0;c2<CC2;c2+=4){
      float4 v = ld4(rr + c2);
      #pragma unroll
      for (int c=0;c<CC3;++c){
        acc[c] += v.x * w[((c*CC2+c2  )<<4)+k]
                + v.y * w[((c*CC2+c2+1)<<4)+k]
                + v.z * w[((c*CC2+c2+2)<<4)+k]
                + v.w * w[((c*CC2+c2+3)<<4)+k];
      }
    }
  }
  u16* o = out + (size_t)idx*CC3;
  #pragma unroll
  for (int c=0;c<CC3;++c) o[c] = f2bf(fmaxf(acc[c], 0.f));
}

// ---------------------------------------------------------------------------
// weight prep, FRAGMENT-MAJOR: entry E = ((((bid*2+wt)*4+kq)*NIT+it)*64+lane),
// 16B per entry per plane. lane = q*16 + r; weight row R = bid*32+wt*16+r;
// grow = gate*1024 + (R>>5)*8 + (R&7), gate=(R&31)>>3; k = it*128+kq*32+q*8+e.
// ---------------------------------------------------------------------------
__global__ __launch_bounds__(256) void prep_kernel(const float* __restrict__ wih,
    const float* __restrict__ whh, u16* __restrict__ wh, u16* __restrict__ wl,
    int Kih, int Kin, int NIT){
  const size_t total = (size_t)128*2*4*NIT*64;
  for (size_t E = (size_t)blockIdx.x*256 + threadIdx.x; E < total;
       E += (size_t)gridDim.x*256){
    int lane = (int)(E & 63);
    size_t t1 = E >> 6;
    int it = (int)(t1 % NIT);  t1 /= NIT;
    int kq = (int)(t1 & 3);    t1 >>= 2;
    int wt = (int)(t1 & 1);    int bid = (int)(t1 >> 1);
    int r = lane & 15, q = lane >> 4;
    int R = bid*32 + wt*16 + r;
    int rl = R & 31, gate = rl >> 3, jj = rl & 7;
    int grow = gate*1024 + (R >> 5)*8 + jj;
    int k0 = it*128 + kq*32 + q*8;
    u16 hv[8], lv[8];
    #pragma unroll
    for (int e=0; e<8; ++e){
      int k = k0 + e;
      float v = 0.f;
      if (k < Kih)      v = wih[(size_t)grow*Kih + k];
      else if (k < Kin) v = whh[(size_t)grow*HH + (k - Kih)];
      u16 h = f2bf(v);
      hv[e] = h;
      lv[e] = f2bf(v - bf2f(h));
    }
    *(ulonglong2*)(wh + E*8) = *(ulonglong2*)hv;
    *(ulonglong2*)(wl + E*8) = *(ulonglong2*)lv;
  }
}

__global__ __launch_bounds__(256) void bsum_kernel(
    const float* __restrict__ bih1, const float* __restrict__ bhh1,
    const float* __restrict__ bih2, const float* __restrict__ bhh2,
    const float* __restrict__ bih3, const float* __restrict__ bhh3,
    float* __restrict__ bs0, float* __restrict__ bs1, float* __restrict__ bs2){
  int idx = blockIdx.x*256 + threadIdx.x;
  if (idx < 4096)       bs0[idx] = bih1[idx] + bhh1[idx];
  else if (idx < 8192){ int r=idx-4096; bs1[r] = bih2[r] + bhh2[r]; }
  else if (idx < 12288){int r=idx-8192; bs2[r] = bih3[r] + bhh3[r]; }
}

__global__ void barinit_kernel(u32* bar){
  for (int i = threadIdx.x; i < 512; i += 256) bar[i] = 0u;
}

// ---------------------------------------------------------------------------
struct SeqArgs {
  const float *x;
  const float *wa[3];
  const float *wout, *bout;
  const u16 *enc;
  const u16 *wwh[3], *wwl[3];
  const float *bsum[3];
  u16 *pl[3][2][2];            // fragment-major x planes
  float *hbuf;
  float *cbuf;
  float *dout;
  u32 *slots;
  u32 *go;
};

#define SMEM_FLOATS 5376

__device__ __forceinline__ void gbar(const SeqArgs& A, u32 nb){
  asm volatile("s_waitcnt vmcnt(0)" ::: "memory");
  __syncthreads();
  const int bid = blockIdx.x, tid = threadIdx.x;
  if (tid == 0)
    __hip_atomic_store(A.slots + bid, nb, __ATOMIC_RELEASE,
                       __HIP_MEMORY_SCOPE_AGENT);
  if (bid == 0){
    if (tid < 64){
      for (;;){
        u32 v0 = lda32u(A.slots + tid);
        u32 v1 = lda32u(A.slots + 64 + tid);
        u32 v2 = lda32u(A.slots + 128 + tid);
        u32 v3 = lda32u(A.slots + 192 + tid);
        u32 mn = min(min(v0,v1), min(v2,v3));
        if (__all(mn >= nb)) break;
        __builtin_amdgcn_s_sleep(4);
      }
      if (tid == 0) sta32(A.go, nb);
    }
  } else if (tid == 0){
    while (lda32u(A.go) < nb) __builtin_amdgcn_s_sleep(4);
  }
  __syncthreads();
}

// attend for (l,b) parity par: q = wa^T h ; softmax(enc.q) ; ctx -> plane
__device__ void attend_phase(const SeqArgs& A, int l, int par, int b, float* sm){
  const int tid = threadIdx.x;
  const float* wa = A.wa[l];
  const float* h  = A.hbuf + (size_t)((l*2+par)*BB + b)*HH;
  const int NITl = (l==0)? NIT0 : NIT12;
  u16* ch = A.pl[l][par][0];
  u16* cl = A.pl[l][par][1];
  float* sh  = sm;
  float* sq  = sm + 1024;
  float* ss  = sm + 1056;
  float* red = sm + 3104;
  float* ctxf= sm + 4128;

  sh[tid] = lda32f(h + tid);
  __syncthreads();

  const int cc = tid&31, g = tid>>5;
  float part = 0.f;
  for (int kk=g; kk<HH; kk+=32) part += wa[kk*32+cc]*sh[kk];
  red[tid] = part; __syncthreads();
  if (tid<32){ float s=0.f;
    #pragma unroll
    for (int gg=0; gg<32; ++gg) s += red[gg*32+tid];
    sq[tid]=s; }
  __syncthreads();

  const u16* eb = A.enc + (size_t)b*LL3*CC3;
  float lmax = -1e30f;
  for (int t=tid; t<LL3; t+=1024){
    const u16* er = eb + t*32; float dot=0.f;
    #pragma unroll
    for (int c4=0;c4<8;++c4){
      u64 w = *(const u64*)(er + c4*4);
      dot += bfq(w,0)*sq[c4*4] + bfq(w,1)*sq[c4*4+1]
           + bfq(w,2)*sq[c4*4+2] + bfq(w,3)*sq[c4*4+3];
    }
    ss[t]=dot; lmax=fmaxf(lmax,dot);
  }
  #pragma unroll
  for (int o=32;o>0;o>>=1) lmax = fmaxf(lmax, __shfl_xor(lmax,o));
  if ((tid&63)==0) red[tid>>6] = lmax;
  __syncthreads();
  if (tid==0){ float m=red[0]; for (int w=1;w<16;++w) m=fmaxf(m,red[w]); red[16]=m; }
  __syncthreads();
  const float m = red[16];

  float lsum = 0.f;
  for (int t=tid; t<LL3; t+=1024){ float e=__expf(ss[t]-m); ss[t]=e; lsum+=e; }
  #pragma unroll
  for (int o=32;o>0;o>>=1) lsum += __shfl_xor(lsum,o);
  if ((tid&63)==0) red[32 + (tid>>6)] = lsum;
  __syncthreads();
  if (tid==0){ float z=0.f; for (int w=0;w<16;++w) z+=red[32+w]; red[17]=1.0f/z; }
  __syncthreads();
  const float rZ = red[17];

  float acc = 0.f;
  for (int t=g; t<LL3; t+=32) acc += ss[t]*bf2f(eb[t*32+cc]);
  __syncthreads();
  red[tid] = acc; __syncthreads();
  if (tid<32){ float s=0.f;
    #pragma unroll
    for (int gg=0; gg<32; ++gg) s += red[gg*32+tid];
    ctxf[tid] = s*rZ; }
  __syncthreads();
  if (tid < 16){
    float v0=ctxf[2*tid], v1=ctxf[2*tid+1];
    sta32((u32*)ch + xidx(NITl, b, 2*tid), (u32)f2bf(v0) | ((u32)f2bf(v1)<<16));
  } else if (tid < 32){
    int t2 = tid-16;
    float v0=ctxf[2*t2], v1=ctxf[2*t2+1];
    u16 h0=f2bf(v0), h1=f2bf(v1);
    sta32((u32*)cl + xidx(NITl, b, 2*t2),
          (u32)f2bf(v0-bf2f(h0)) | ((u32)f2bf(v1-bf2f(h1))<<16));
  }
}

// out phase: y(s) -> dout[:,s,:]; y -> prev slot (k=32..96) of l0 plane pn.
__device__ void out_phase(const SeqArgs& A, int pn, int s, int b, float* sm){
  float* sh = sm; float* red = sm+1024; float* yv = sm+2048;
  const int tid = threadIdx.x;
  sh[tid] = lda32f(A.hbuf + (size_t)((2*2+pn)*BB + b)*HH + tid);
  __syncthreads();
  const int d = tid&63, kg = tid>>6;
  const float* wr = A.wout + (size_t)d*HH + kg*64;
  const float* hh = sh + kg*64;
  float acc = 0.f;
  #pragma unroll
  for (int k=0;k<64;k+=4){ float4 w4=ld4(wr+k); float4 hv=*(const float4*)&hh[k];
    acc += w4.x*hv.x+w4.y*hv.y+w4.z*hv.z+w4.w*hv.w; }
  red[tid]=acc; __syncthreads();
  if (tid<64){
    float y = A.bout[tid];
    #pragma unroll
    for (int kk=0;kk<16;++kk) y += red[kk*64+tid];
    A.dout[((size_t)b*NSTEP+s)*DOUT+tid] = y;
    yv[tid] = y;
  }
  __syncthreads();
  if (tid < 32){
    float v0=yv[2*tid], v1=yv[2*tid+1];
    sta32((u32*)A.pl[0][pn][0] + xidx(NIT0, b, 32 + 2*tid),
          (u32)f2bf(v0) | ((u32)f2bf(v1)<<16));
  } else if (tid < 64){
    int t2 = tid-32;
    float v0=yv[2*t2], v1=yv[2*t2+1];
    u16 h0=f2bf(v0), h1=f2bf(v1);
    sta32((u32*)A.pl[0][pn][1] + xidx(NIT0, b, 32 + 2*t2),
          (u32)f2bf(v0-bf2f(h0)) | ((u32)f2bf(v1-bf2f(h1))<<16));
  }
}

// MFMA GEMM + fused cell. Fragment-major: per wave, loads are contiguous
// 1KB (weights, plain) / 2x512B (x, coherent atomics) per iteration.
template<int L, int NIT>
__device__ void gemm_phase(const SeqArgs& A, int p, int pn, float* sm){
  const int bid = blockIdx.x, tid = threadIdx.x;
  const u16* wh  = A.wwh[L];
  const u16* wlo = A.wwl[L];
  const u16* ih = A.pl[L][p][0];
  const u16* il = A.pl[L][p][1];
  const int wave = tid>>6, lane = tid&63;
  const int wt = wave>>3, xh = (wave>>2)&1, kq = wave&3;
  const size_t wbase = ((((size_t)bid*2 + wt)*4 + kq)*NIT)*512 + lane*8;
  const size_t xbase = (((size_t)xh*4 + kq)*NIT)*512 + lane*8;
  const u16* wph = wh  + wbase;
  const u16* wpl = wlo + wbase;
  const u16* xb  = ih + xbase;
  const u16* xlb = il + xbase;

  f32x4 acc0 = {0.f,0.f,0.f,0.f}, acc1 = {0.f,0.f,0.f,0.f}, acc2 = {0.f,0.f,0.f,0.f};
  bf16x8 whA, wlA, whB, wlB;
  FR xhA, xlA, xhB, xlB;
  whA = *(const bf16x8*)(wph);
  wlA = *(const bf16x8*)(wpl);
  xhA.q[0] = lda64(xb);    xhA.q[1] = lda64(xb+4);
  xlA.q[0] = lda64(xlb);   xlA.q[1] = lda64(xlb+4);
  #pragma unroll
  for (int it = 0; it < NIT; ++it){
    const int o = (it+1)*512;
    if ((it & 1) == 0){
      if (it+1 < NIT){
        whB = *(const bf16x8*)(wph + o);
        wlB = *(const bf16x8*)(wpl + o);
        xhB.q[0] = lda64(xb+o);  xhB.q[1] = lda64(xb+o+4);
        xlB.q[0] = lda64(xlb+o); xlB.q[1] = lda64(xlb+o+4);
      }
      acc0 = __builtin_amdgcn_mfma_f32_16x16x32_bf16(xhA.v, whA, acc0, 0,0,0);
      acc1 = __builtin_amdgcn_mfma_f32_16x16x32_bf16(xlA.v, whA, acc1, 0,0,0);
      acc2 = __builtin_amdgcn_mfma_f32_16x16x32_bf16(xhA.v, wlA, acc2, 0,0,0);
    } else {
      if (it+1 < NIT){
        whA = *(const bf16x8*)(wph + o);
        wlA = *(const bf16x8*)(wpl + o);
        xhA.q[0] = lda64(xb+o);  xhA.q[1] = lda64(xb+o+4);
        xlA.q[0] = lda64(xlb+o); xlA.q[1] = lda64(xlb+o+4);
      }
      acc0 = __builtin_amdgcn_mfma_f32_16x16x32_bf16(xhB.v, whB, acc0, 0,0,0);
      acc1 = __builtin_amdgcn_mfma_f32_16x16x32_bf16(xlB.v, whB, acc1, 0,0,0);
      acc2 = __builtin_amdgcn_mfma_f32_16x16x32_bf16(xhB.v, wlB, acc2, 0,0,0);
    }
  }
  f32x4 acc = acc0 + acc1 + acc2;

  float* red = sm;            // 16*256
  float* sg  = sm + 4096;     // 32*32
  float* hv  = sm + 5120;     // 8*32
  #pragma unroll
  for (int rg=0; rg<4; ++rg) red[wave*256 + lane*4 + rg] = acc[rg];
  __syncthreads();
  {
    const int tile = tid>>8, e = tid&255;
    const int wt2 = tile>>1, xh2 = tile&1;
    const int base = (wt2*8 + xh2*4)*256 + e;
    float v = red[base] + red[base+256] + red[base+512] + red[base+768];
    const int ln = e>>2, rg = e&3;
    // D layout (m89): col=lane&15 -> weight row, row=4*(lane>>4)+reg -> batch
    sg[(wt2*16 + (ln&15))*32 + xh2*16 + ((ln>>4)<<2) + rg] = v;
  }
  __syncthreads();
  if (tid < 256){
    const int b = tid&31, jj = tid>>5;
    const int j = bid*8 + jj;
    const float* bs = A.bsum[L];
    float gi = sg[(0 +jj)*32+b] + bs[j];
    float gf = sg[(8 +jj)*32+b] + bs[1024+j];
    float gg = sg[(16+jj)*32+b] + bs[2048+j];
    float go = sg[(24+jj)*32+b] + bs[3072+j];
    float i_ = 1.f/(1.f+__expf(-gi));
    float f_ = 1.f/(1.f+__expf(-gf));
    float g_ = tanhf(gg);
    float o_ = 1.f/(1.f+__expf(-go));
    float* cb = A.cbuf + ((size_t)L*BB + b)*HH + j;
    float c = f_*cb[0] + i_*g_;
    cb[0] = c;
    float hval = o_*tanhf(c);
    sta32f(A.hbuf + ((size_t)(L*2+pn)*BB + b)*HH + j, hval);
    hv[jj*32 + b] = hval;
  }
  __syncthreads();
  if (tid < 128){
    const int b = tid&31, pr = tid>>5;
    const int jj0 = pr*2;
    float v0 = hv[jj0*32+b], v1 = hv[(jj0+1)*32+b];
    u16 h0 = f2bf(v0), h1 = f2bf(v1);
    u32 ph  = (u32)h0 | ((u32)h1<<16);
    u32 plq = (u32)f2bf(v0-bf2f(h0)) | ((u32)f2bf(v1-bf2f(h1))<<16);
    const int col = bid*8 + jj0;
    if (L == 0){
      u32 i1 = xidx(NIT0,  b, 96 + col);     // own h1, next step
      sta32((u32*)A.pl[0][pn][0] + i1, ph);  sta32((u32*)A.pl[0][pn][1] + i1, plq);
      u32 i2 = xidx(NIT12, b, 32 + col);     // L2 input, this step
      sta32((u32*)A.pl[1][p ][0] + i2, ph);  sta32((u32*)A.pl[1][p ][1] + i2, plq);
    } else if (L == 1){
      u32 i1 = xidx(NIT12, b, 1056 + col);   // own h2, next step
      sta32((u32*)A.pl[1][pn][0] + i1, ph);  sta32((u32*)A.pl[1][pn][1] + i1, plq);
      u32 i2 = xidx(NIT12, b, 32 + col);     // L3 input, this step
      sta32((u32*)A.pl[2][p ][0] + i2, ph);  sta32((u32*)A.pl[2][p ][1] + i2, plq);
    } else {
      u32 i1 = xidx(NIT12, b, 1056 + col);   // own h3, next step
      sta32((u32*)A.pl[2][pn][0] + i1, ph);  sta32((u32*)A.pl[2][pn][1] + i1, plq);
    }
  }
}

__global__ __launch_bounds__(1024, 4) void seq_kernel(SeqArgs A){
  __shared__ float sm[SMEM_FLOATS];
  const int bid = blockIdx.x, tid = threadIdx.x;
  const size_t gid = (size_t)bid*1024 + tid;
  const size_t gstr = (size_t)256*1024;
  u32 nb = 0;

  // ---- init: zero ALL planes (whole arrays incl pads), hbuf par0, cbuf ----
  {
    const size_t n0 = (size_t)32*(KP0>>1);      // 18432 u32 per l0 buffer
    const size_t n1 = (size_t)32*(KP12>>1);     // 34816 u32 per l1/l2 buffer
    for (size_t i = gid; i < n0; i += gstr){
      #pragma unroll
      for (int q=0;q<2;++q)
        #pragma unroll
        for (int hl=0;hl<2;++hl)
          sta32((u32*)A.pl[0][q][hl] + i, 0u);
    }
    for (size_t i = gid; i < n1; i += gstr){
      #pragma unroll
      for (int q=0;q<2;++q)
        #pragma unroll
        for (int hl=0;hl<2;++hl){
          sta32((u32*)A.pl[1][q][hl] + i, 0u);
          sta32((u32*)A.pl[2][q][hl] + i, 0u);
        }
    }
  }
  for (size_t i = gid; i < (size_t)3*32*1024; i += gstr){
    size_t l2 = i >> 15, r = i & 32767, b = r >> 10, j = r & 1023;
    sta32f(A.hbuf + ((l2*2+0)*BB + b)*HH + j, 0.f);
  }
  if (bid < 128){
    for (int t = tid; t < 3*32*8; t += 1024){
      int l2 = t/(32*8), r = t%(32*8), b = r>>3, jj = r&7;
      A.cbuf[((size_t)l2*BB + b)*HH + bid*8 + jj] = 0.f;
    }
  }
  gbar(A, ++nb);

  // P0: att1/2/3(0) at parity 0 ; prev(0) = x[:,T-1,:] into l0 plane par0.
  if (bid >= 128 && bid < 224){
    int l = (bid-128)>>5, b = (bid-128)&31;
    attend_phase(A, l, 0, b, sm);
  } else if (bid >= 224){
    int b = bid - 224;
    if (tid < 64 && (tid & 1) == 0){
      float v  = A.x[((size_t)b*TT + (TT-1))*DIN + tid];
      float v1 = A.x[((size_t)b*TT + (TT-1))*DIN + tid + 1];
      u16 h = f2bf(v), h1 = f2bf(v1);
      u32 idx = xidx(NIT0, b, 32 + tid);
      sta32((u32*)A.pl[0][0][0] + idx, (u32)h | ((u32)h1<<16));
      u16 l0 = f2bf(v - bf2f(h)), l1 = f2bf(v1 - bf2f(h1));
      sta32((u32*)A.pl[0][0][1] + idx, (u32)l0 | ((u32)l1<<16));
    }
  }
  gbar(A, ++nb);

  for (int s = 0; s < NSTEP; ++s){
    const int p = s&1, pn = p^1;
    // P1: G1(s)
    if (bid < 128) gemm_phase<0,NIT0>(A, p, pn, sm);
    gbar(A, ++nb);
    // P2: G2(s) || att1(s+1)
    if (bid < 128)        gemm_phase<1,NIT12>(A, p, pn, sm);
    else if (bid < 160)   attend_phase(A, 0, pn, bid-128, sm);
    gbar(A, ++nb);
    // P3: G3(s) || att2(s+1)
    if (bid < 128)        gemm_phase<2,NIT12>(A, p, pn, sm);
    else if (bid < 160)   attend_phase(A, 1, pn, bid-128, sm);
    gbar(A, ++nb);
    // P4: out(s) || att3(s+1)
    if (bid >= 128 && bid < 160)      out_phase(A, pn, s, bid-128, sm);
    else if (bid >= 160 && bid < 192) attend_phase(A, 2, pn, bid-160, sm);
    gbar(A, ++nb);
  }
}

// ---------------------------------------------------------------------------
extern "C" void kernel_launch(void* const* d_in, const int* in_sizes, int n_in,
                              void* d_out, int out_size, void* d_ws, size_t ws_size,
                              hipStream_t stream) {
  const float* x    = (const float*)d_in[0];
  const float* w_c1 = (const float*)d_in[1];
  const float* b_c1 = (const float*)d_in[2];
  const float* w_c2 = (const float*)d_in[3];
  const float* b_c2 = (const float*)d_in[4];
  const float* w_c3 = (const float*)d_in[5];
  const float* b_c3 = (const float*)d_in[6];

  SeqArgs A;
  A.x     = x;
  A.wa[0] = (const float*)d_in[7];
  A.wa[1] = (const float*)d_in[9];
  A.wa[2] = (const float*)d_in[11];
  const float* wih1 = (const float*)d_in[13];
  const float* whh1 = (const float*)d_in[14];
  const float* bih1 = (const float*)d_in[15];
  const float* bhh1 = (const float*)d_in[16];
  const float* wih2 = (const float*)d_in[17];
  const float* whh2 = (const float*)d_in[18];
  const float* bih2 = (const float*)d_in[19];
  const float* bhh2 = (const float*)d_in[20];
  const float* wih3 = (const float*)d_in[21];
  const float* whh3 = (const float*)d_in[22];
  const float* bih3 = (const float*)d_in[23];
  const float* bhh3 = (const float*)d_in[24];
  A.wout = (const float*)d_in[25];
  A.bout = (const float*)d_in[26];
  A.dout = (float*)d_out;

  char* base = (char*)d_ws;
  size_t off = 0;
  auto alloc = [&](size_t bytes)->char*{
    char* pp = base + off; off = (off + bytes + 255) & ~(size_t)255; return pp;
  };

  u16* enc = (u16*)alloc((size_t)BB*LL3*CC3*2);
  A.enc  = enc;
  A.hbuf = (float*)alloc((size_t)3*2*BB*HH*4);
  A.cbuf = (float*)alloc((size_t)3*BB*HH*4);
  for (int l=0;l<3;++l){
    size_t kp = (l==0)? KP0 : KP12;
    for (int par=0; par<2; ++par)
      for (int hl=0; hl<2; ++hl)
        A.pl[l][par][hl] = (u16*)alloc((size_t)BB*kp*2);
  }
  float* bs0 = (float*)alloc(4096*4);
  float* bs1 = (float*)alloc(4096*4);
  float* bs2 = (float*)alloc(4096*4);
  A.bsum[0]=bs0; A.bsum[1]=bs1; A.bsum[2]=bs2;
  u32* bar = (u32*)alloc(4096);
  A.slots = bar;
  A.go    = bar + 320;
  u16 *wp[6];
  wp[0] = (u16*)alloc((size_t)4096*KP0*2);
  wp[1] = (u16*)alloc((size_t)4096*KP0*2);
  wp[2] = (u16*)alloc((size_t)4096*KP12*2);
  wp[3] = (u16*)alloc((size_t)4096*KP12*2);
  wp[4] = (u16*)alloc((size_t)4096*KP12*2);
  wp[5] = (u16*)alloc((size_t)4096*KP12*2);
  A.wwh[0]=wp[0]; A.wwl[0]=wp[1];
  A.wwh[1]=wp[2]; A.wwl[1]=wp[3];
  A.wwh[2]=wp[4]; A.wwl[2]=wp[5];

  // conv temps alias the layer-1 hi weight buffer (preps run after convs)
  float* r1 = (float*)wp[0];
  float* r2 = (float*)(((char*)wp[0]) + 2095104);

  conv1_kernel<<<(BB*LL1+255)/256, 256, 0, stream>>>(x, w_c1, b_c1, r1);
  conv2_kernel<<<(BB*LL2+255)/256, 256, 0, stream>>>(r1, w_c2, b_c2, r2);
  conv3_kernel<<<(BB*LL3+255)/256, 256, 0, stream>>>(r2, w_c3, b_c3, enc);
  prep_kernel<<<2048, 256, 0, stream>>>(wih1, whh1, wp[0], wp[1],   96, K0,  NIT0);
  prep_kernel<<<2048, 256, 0, stream>>>(wih2, whh2, wp[2], wp[3], 1056, K12, NIT12);
  prep_kernel<<<2048, 256, 0, stream>>>(wih3, whh3, wp[4], wp[5], 1056, K12, NIT12);
  bsum_kernel<<<48, 256, 0, stream>>>(bih1,bhh1,bih2,bhh2,bih3,bhh3, bs0,bs1,bs2);
  barinit_kernel<<<1, 256, 0, stream>>>(bar);

  void* params[] = { (void*)&A };
  hipLaunchCooperativeKernel((const void*)seq_kernel, dim3(256), dim3(1024),
                             params, 0, stream);
}